// Round 3
// baseline (12780.108 us; speedup 1.0000x reference)
//
#include <hip/hip_runtime.h>
#include <hip/hip_bf16.h>

// Informer forward, MI355X. Round 3 (fixed): runtime input-dtype sniffing (fp32 vs bf16),
// bf16 internal pipeline, element-offset plumbing for raw-input sub-arrays,
// conv-out region overflow fixed (V region 8.5 MiB).
// B=16, LE=512, LD=256, D=512, H=8, dk=64, DFF=2048, NE=3, ND=2, TOPK=16.
// Encoder lengths: 512 -> conv(514)/pool -> 257 -> conv(259)/pool -> 130.

#define DM 512
#define DK 64

using bf16 = __hip_bfloat16;

__device__ inline float b2f(bf16 x) { return __bfloat162float(x); }
__device__ inline float u2f(unsigned short u) { return __uint_as_float((unsigned)u << 16); }

// flag f: 1 = raw inputs are bf16, 0 = raw inputs are fp32. idx in ELEMENTS.
__device__ inline float ldw(const void* p, unsigned i, int f) {
    return f ? b2f(((const bf16*)p)[i]) : ((const float*)p)[i];
}

// ---------------- dtype sniffer ----------------
// Words with bits14..7 == 0x7F <=> low-half bf16 magnitude in [1,2): ~27% for bf16
// N(0,1) data, ~0.4% for fp32 mantissa bits.
__global__ __launch_bounds__(256) void sniff_k(const unsigned* __restrict__ x, int nwords,
                                               int* __restrict__ flag) {
    __shared__ int red[4];
    const int t = threadIdx.x;
    int c = 0;
    for (int i = t; i < nwords; i += 256) c += ((x[i] & 0x7F80u) == 0x3F80u) ? 1 : 0;
    #pragma unroll
    for (int o = 32; o > 0; o >>= 1) c += __shfl_down(c, o);
    __syncthreads();
    if ((t & 63) == 0) red[t >> 6] = c;
    __syncthreads();
    if (t == 0) flag[0] = (red[0] + red[1] + red[2] + red[3] > nwords / 20) ? 1 : 0;
}

// ---------------- reductions (blockDim == 256) ----------------
__device__ inline float block_sum256(float v, float* red) {
    #pragma unroll
    for (int o = 32; o > 0; o >>= 1) v += __shfl_down(v, o);
    __syncthreads();
    if ((threadIdx.x & 63) == 0) red[threadIdx.x >> 6] = v;
    __syncthreads();
    return red[0] + red[1] + red[2] + red[3];
}
__device__ inline float block_max256(float v, float* red) {
    #pragma unroll
    for (int o = 32; o > 0; o >>= 1) v = fmaxf(v, __shfl_down(v, o));
    __syncthreads();
    if ((threadIdx.x & 63) == 0) red[threadIdx.x >> 6] = v;
    __syncthreads();
    return fmaxf(fmaxf(red[0], red[1]), fmaxf(red[2], red[3]));
}

// ---------------- embedding ----------------
__global__ __launch_bounds__(256) void embed_k(
    const void* __restrict__ xv, const void* __restrict__ vw, const void* __restrict__ vb,
    const void* __restrict__ xm, const void* __restrict__ mw, const void* __restrict__ mb,
    bf16* __restrict__ Out, int rows, int Cv, int Cm, const int* __restrict__ flagp)
{
    const int f = *flagp;
    int i = blockIdx.x * 256 + threadIdx.x;
    if (i >= rows * DM) return;
    const int r = i >> 9, d = i & 511;
    float acc = ldw(vb, d, f) + ldw(mb, d, f);
    for (int c = 0; c < Cv; ++c) acc += ldw(xv, r * Cv + c, f) * ldw(vw, c * DM + d, f);
    for (int c = 0; c < Cm; ++c) acc += ldw(xm, r * Cm + c, f) * ldw(mw, c * DM + d, f);
    Out[i] = __float2bfloat16(acc);
}

// ---------------- GEMM: C[M,N] = A[M,K] @ W[woff0 + K,N] + bias[boff0..], opt ReLU ----
// A internal bf16; W/bias raw inputs with element offsets; fp32 accumulate.
template<bool RELU>
__global__ __launch_bounds__(256) void gemm_off_k(
    const bf16* __restrict__ A,
    const void* __restrict__ W, unsigned woff0,
    const void* __restrict__ bias, unsigned boff0,
    bf16* __restrict__ C, int M, int N, int K, const int* __restrict__ flagp)
{
    __shared__ float As[16][64];
    __shared__ float Ws[16][64];
    const int f = *flagp;
    const int t = threadIdx.x;
    const int bm = blockIdx.y * 64, bn = blockIdx.x * 64;
    const int tx = t & 15, ty = t >> 4;
    const int am = t & 63, akq = t >> 6;
    const int wn = (t & 15) * 4, wk = t >> 4;
    const int mrow = bm + am;
    const bool avalid = mrow < M;

    float acc[4][4] = {};

    for (int k0 = 0; k0 < K; k0 += 16) {
        ushort4 a4 = make_ushort4(0, 0, 0, 0);
        if (avalid)
            a4 = *reinterpret_cast<const ushort4*>(A + (size_t)mrow * K + k0 + akq * 4);
        As[akq * 4 + 0][am] = u2f(a4.x);
        As[akq * 4 + 1][am] = u2f(a4.y);
        As[akq * 4 + 2][am] = u2f(a4.z);
        As[akq * 4 + 3][am] = u2f(a4.w);
        const unsigned woff = woff0 + (unsigned)(k0 + wk) * N + bn + wn;
        float w0, w1, w2, w3;
        if (f) {
            const ushort4 u = *reinterpret_cast<const ushort4*>((const bf16*)W + woff);
            w0 = u2f(u.x); w1 = u2f(u.y); w2 = u2f(u.z); w3 = u2f(u.w);
        } else {
            const float4 v = *reinterpret_cast<const float4*>((const float*)W + woff);
            w0 = v.x; w1 = v.y; w2 = v.z; w3 = v.w;
        }
        Ws[wk][wn + 0] = w0;
        Ws[wk][wn + 1] = w1;
        Ws[wk][wn + 2] = w2;
        Ws[wk][wn + 3] = w3;
        __syncthreads();
        #pragma unroll
        for (int kk = 0; kk < 16; ++kk) {
            const float4 a = *reinterpret_cast<const float4*>(&As[kk][ty * 4]);
            const float4 w = *reinterpret_cast<const float4*>(&Ws[kk][tx * 4]);
            const float av[4] = {a.x, a.y, a.z, a.w};
            #pragma unroll
            for (int i = 0; i < 4; ++i) {
                acc[i][0] += av[i] * w.x;
                acc[i][1] += av[i] * w.y;
                acc[i][2] += av[i] * w.z;
                acc[i][3] += av[i] * w.w;
            }
        }
        __syncthreads();
    }

    float bv[4];
    #pragma unroll
    for (int j = 0; j < 4; ++j) bv[j] = ldw(bias, boff0 + bn + tx * 4 + j, f);
    #pragma unroll
    for (int i = 0; i < 4; ++i) {
        const int row = bm + ty * 4 + i;
        if (row < M) {
            #pragma unroll
            for (int j = 0; j < 4; ++j) {
                float o = acc[i][j] + bv[j];
                if (RELU) o = fmaxf(o, 0.f);
                C[(size_t)row * N + bn + tx * 4 + j] = __float2bfloat16(o);
            }
        }
    }
}

// ---------------- conv GEMM: K=1536 over 3 gathered taps; W internal bf16 ----------------
__global__ __launch_bounds__(256) void gemm3_k(
    const bf16* __restrict__ A, const int* __restrict__ ridx,
    const bf16* __restrict__ W,
    const void* __restrict__ bias, unsigned boff0,
    bf16* __restrict__ C, int M, int N, const int* __restrict__ flagp)
{
    __shared__ float As[16][64];
    __shared__ float Ws[16][64];
    const int f = *flagp;
    const int t = threadIdx.x;
    const int bm = blockIdx.y * 64, bn = blockIdx.x * 64;
    const int tx = t & 15, ty = t >> 4;
    const int am = t & 63, akq = t >> 6;
    const int wn = (t & 15) * 4, wk = t >> 4;
    const int mrow = bm + am;
    const bool avalid = mrow < M;

    float acc[4][4] = {};

    for (int k0 = 0; k0 < 1536; k0 += 16) {
        ushort4 a4 = make_ushort4(0, 0, 0, 0);
        if (avalid) {
            const int r = ridx[(k0 >> 9) * M + mrow];
            a4 = *reinterpret_cast<const ushort4*>(A + (size_t)r * 512 + (k0 & 511) + akq * 4);
        }
        As[akq * 4 + 0][am] = u2f(a4.x);
        As[akq * 4 + 1][am] = u2f(a4.y);
        As[akq * 4 + 2][am] = u2f(a4.z);
        As[akq * 4 + 3][am] = u2f(a4.w);
        const ushort4 u = *reinterpret_cast<const ushort4*>(W + (size_t)(k0 + wk) * N + bn + wn);
        Ws[wk][wn + 0] = u2f(u.x);
        Ws[wk][wn + 1] = u2f(u.y);
        Ws[wk][wn + 2] = u2f(u.z);
        Ws[wk][wn + 3] = u2f(u.w);
        __syncthreads();
        #pragma unroll
        for (int kk = 0; kk < 16; ++kk) {
            const float4 a = *reinterpret_cast<const float4*>(&As[kk][ty * 4]);
            const float4 w = *reinterpret_cast<const float4*>(&Ws[kk][tx * 4]);
            const float av[4] = {a.x, a.y, a.z, a.w};
            #pragma unroll
            for (int i = 0; i < 4; ++i) {
                acc[i][0] += av[i] * w.x;
                acc[i][1] += av[i] * w.y;
                acc[i][2] += av[i] * w.z;
                acc[i][3] += av[i] * w.w;
            }
        }
        __syncthreads();
    }

    float bv[4];
    #pragma unroll
    for (int j = 0; j < 4; ++j) bv[j] = ldw(bias, boff0 + bn + tx * 4 + j, f);
    #pragma unroll
    for (int i = 0; i < 4; ++i) {
        const int row = bm + ty * 4 + i;
        if (row < M) {
            #pragma unroll
            for (int j = 0; j < 4; ++j)
                C[(size_t)row * N + bn + tx * 4 + j] = __float2bfloat16(acc[i][j] + bv[j]);
        }
    }
}

// ---------------- attention: one block per (b,h,q); O written in-place over Q ----------------
template<bool TOPK_ON, bool CAUSAL>
__global__ __launch_bounds__(256) void attn_k(
    bf16* __restrict__ Q, const bf16* __restrict__ Kv,
    const bf16* __restrict__ Vv, int Lq, int Lk)
{
    __shared__ float qs[DK];
    __shared__ float s[512];
    __shared__ float sc[TOPK_ON ? 512 : 1];
    __shared__ float part[4][DK];
    __shared__ float red[4];
    __shared__ int   redi[4];
    __shared__ float bcast[1];

    const int t = threadIdx.x;
    const int q = blockIdx.x, h = blockIdx.y, b = blockIdx.z;

    bf16* Qp = Q + ((size_t)b * Lq + q) * DM + h * DK;
    if (t < DK) qs[t] = b2f(Qp[t]);
    __syncthreads();

    for (int k = t; k < Lk; k += 256) {
        const bf16* Kp = Kv + ((size_t)b * Lk + k) * DM + h * DK;
        float acc = 0.f;
        #pragma unroll
        for (int d = 0; d < DK; d += 4) {
            const ushort4 kv = *reinterpret_cast<const ushort4*>(Kp + d);
            acc += qs[d] * u2f(kv.x) + qs[d + 1] * u2f(kv.y)
                 + qs[d + 2] * u2f(kv.z) + qs[d + 3] * u2f(kv.w);
        }
        acc *= 0.125f;  // 1/sqrt(64)
        if (CAUSAL && k > q) acc -= 1e9f;
        s[k] = acc;
        if (TOPK_ON) sc[k] = acc;
    }
    __syncthreads();

    float m, kth = 0.f;
    if (TOPK_ON) {
        float mx0 = 0.f, last = 0.f;
        for (int it = 0; it < 16; ++it) {
            float lv = -INFINITY; int li = 0;
            for (int k = t; k < Lk; k += 256)
                if (sc[k] > lv) { lv = sc[k]; li = k; }
            #pragma unroll
            for (int o = 32; o > 0; o >>= 1) {
                const float ov = __shfl_down(lv, o);
                const int   oi = __shfl_down(li, o);
                if (ov > lv) { lv = ov; li = oi; }
            }
            if ((t & 63) == 0) { red[t >> 6] = lv; redi[t >> 6] = li; }
            __syncthreads();
            if (t == 0) {
                float bvv = red[0]; int bi = redi[0];
                #pragma unroll
                for (int w = 1; w < 4; ++w)
                    if (red[w] > bvv) { bvv = red[w]; bi = redi[w]; }
                sc[bi] = -INFINITY;
                bcast[0] = bvv;
            }
            __syncthreads();
            const float bvv = bcast[0];
            if (it == 0) mx0 = bvv;
            last = bvv;
        }
        m = mx0; kth = last;
    } else {
        float lv = -INFINITY;
        for (int k = t; k < Lk; k += 256) lv = fmaxf(lv, s[k]);
        m = block_max256(lv, red);
    }

    float dpart = 0.f;
    for (int k = t; k < Lk; k += 256) {
        const float sv = s[k];
        float w;
        if (TOPK_ON) w = (sv >= kth) ? expf(sv - m) : 0.f;
        else         w = expf(sv - m);
        s[k] = w;
        dpart += w;
    }
    const float denom = block_sum256(dpart, red);
    const float inv = 1.f / denom;

    const int dd = t & 63, kc = t >> 6;
    float accv = 0.f;
    for (int k = kc; k < Lk; k += 4) {
        const float w = s[k];
        if (w != 0.f)
            accv += w * b2f(Vv[((size_t)b * Lk + k) * DM + h * DK + dd]);
    }
    part[kc][dd] = accv;
    __syncthreads();
    if (t < DK)
        Qp[t] = __float2bfloat16((part[0][t] + part[1][t] + part[2][t] + part[3][t]) * inv);
}

// ---------------- layernorm over D=512, optional residual; in-place safe ----------------
__global__ __launch_bounds__(256) void ln_off_k(
    const bf16* __restrict__ X, const bf16* __restrict__ R,
    const void* __restrict__ gb, unsigned goff,  // gamma at goff+[0,512), beta at goff+[512,1024)
    bf16* __restrict__ Out, const int* __restrict__ flagp)
{
    __shared__ float red[4];
    const int f = *flagp;
    const int t = threadIdx.x;
    const size_t base = (size_t)blockIdx.x * DM;
    float v0 = b2f(X[base + t]), v1 = b2f(X[base + t + 256]);
    if (R) { v0 += b2f(R[base + t]); v1 += b2f(R[base + t + 256]); }
    const float mean = block_sum256(v0 + v1, red) * (1.f / 512.f);
    const float d0 = v0 - mean, d1 = v1 - mean;
    const float var = block_sum256(d0 * d0 + d1 * d1, red) * (1.f / 512.f);
    const float rstd = rsqrtf(var + 1e-5f);
    Out[base + t]       = __float2bfloat16(d0 * rstd * ldw(gb, goff + t, f)       + ldw(gb, goff + 512 + t, f));
    Out[base + t + 256] = __float2bfloat16(d1 * rstd * ldw(gb, goff + t + 256, f) + ldw(gb, goff + 768 + t, f));
}

// ---------------- conv distill helpers ----------------
__global__ __launch_bounds__(256) void convw_k(const void* __restrict__ w, unsigned woff,
                                               bf16* __restrict__ wt, int total,
                                               const int* __restrict__ flagp) {
    // w[o][c][j] (512,512,3) -> wt[j*512+c][o]
    const int f = *flagp;
    int i = blockIdx.x * 256 + threadIdx.x;
    if (i >= total) return;
    const int o = i & 511, c = (i >> 9) & 511, j = i >> 18;
    wt[i] = __float2bfloat16(ldw(w, woff + (o * 512 + c) * 3 + j, f));
}

__global__ __launch_bounds__(256) void convidx_k(int* __restrict__ idx, int Lc, int L, int total) {
    int i = blockIdx.x * 256 + threadIdx.x;
    if (i >= total) return;
    const int j = i / (16 * Lc), mrem = i % (16 * Lc);
    const int b = mrem / Lc, l = mrem % Lc;
    int src = l + j - 2;
    src %= L; if (src < 0) src += L;
    idx[i] = b * L + src;
}

__global__ __launch_bounds__(256) void bnstat1_k(const bf16* __restrict__ Y, float* __restrict__ part, int M) {
    const int t = threadIdx.x;
    float s0 = 0.f, q0 = 0.f, s1 = 0.f, q1 = 0.f;
    for (int r = blockIdx.x; r < M; r += gridDim.x) {
        const ushort2 u = *reinterpret_cast<const ushort2*>(Y + (size_t)r * DM + t * 2);
        const float a = u2f(u.x), c = u2f(u.y);
        s0 += a; q0 += a * a;
        s1 += c; q1 += c * c;
    }
    float* p = part + (size_t)blockIdx.x * 1024;
    p[2 * t] = s0; p[2 * t + 1] = s1;
    p[512 + 2 * t] = q0; p[512 + 2 * t + 1] = q1;
}

__global__ __launch_bounds__(256) void bnstat2_k(const float* __restrict__ part, float* __restrict__ stats,
                                                 int nchunk, int M) {
    const int ch = blockIdx.x * 256 + threadIdx.x;
    if (ch >= 512) return;
    float S = 0.f, Qs = 0.f;
    for (int c = 0; c < nchunk; ++c) { S += part[c * 1024 + ch]; Qs += part[c * 1024 + 512 + ch]; }
    const float mean = S / (float)M;
    const float var = Qs / (float)M - mean * mean;
    stats[ch] = mean;
    stats[512 + ch] = fmaxf(var, 0.f);
}

__global__ __launch_bounds__(256) void bnpool_k(
    const bf16* __restrict__ Yc, const float* __restrict__ stats,
    const void* __restrict__ g, const void* __restrict__ bb, unsigned off,
    bf16* __restrict__ Out, int Lc, int Lout, int total, const int* __restrict__ flagp)
{
    const int f = *flagp;
    int i = blockIdx.x * 256 + threadIdx.x;
    if (i >= total) return;
    const int ch = i & 511;
    const int lp = (i >> 9) % Lout;
    const int b = i / (512 * Lout);
    const float mean = stats[ch], var = stats[512 + ch];
    const float sc = ldw(g, off + ch, f) * rsqrtf(var + 1e-5f);
    const float sh = ldw(bb, off + ch, f) - mean * sc;
    float mx = -INFINITY;
    const int l0 = 2 * lp - 1;
    #pragma unroll
    for (int d = 0; d < 3; ++d) {
        const int l = l0 + d;
        if (l >= 0 && l < Lc) {
            float v = b2f(Yc[((size_t)b * Lc + l) * DM + ch]) * sc + sh;
            v = v > 0.f ? v : expm1f(v);  // ELU
            mx = fmaxf(mx, v);
        }
    }
    Out[((size_t)b * Lout + lp) * DM + ch] = __float2bfloat16(mx);
}

// ---------------- final projection to CO=7, dtype-matched store ----------------
__global__ __launch_bounds__(256) void fc_k(
    const bf16* __restrict__ Yn, const void* __restrict__ fcw, const void* __restrict__ fcb,
    void* __restrict__ out, int total, const int* __restrict__ flagp)
{
    const int f = *flagp;
    int i = blockIdx.x * 256 + threadIdx.x;
    if (i >= total) return;
    const int r = i / 7, co = i % 7;
    const bf16* yr = Yn + (size_t)r * DM;
    float acc = ldw(fcb, co, f);
    for (int d = 0; d < DM; ++d) acc += b2f(yr[d]) * ldw(fcw, d * 7 + co, f);
    if (f) ((bf16*)out)[i] = __float2bfloat16(acc);
    else   ((float*)out)[i] = acc;
}

// =============================================================================
extern "C" void kernel_launch(void* const* d_in, const int* in_sizes, int n_in,
                              void* d_out, int out_size, void* d_ws, size_t ws_size,
                              hipStream_t stream)
{
    const void* x_enc      = d_in[0];
    const void* x_mark_enc = d_in[1];
    const void* x_dec      = d_in[2];
    const void* x_mark_dec = d_in[3];
    const void* enc_vw = d_in[4];
    const void* enc_vb = d_in[5];
    const void* enc_mw = d_in[6];
    const void* enc_mb = d_in[7];
    const void* dec_vw = d_in[8];
    const void* dec_vb = d_in[9];
    const void* dec_mw = d_in[10];
    const void* dec_mb = d_in[11];
    const void* eW    = d_in[12];
    const void* ebi   = d_in[13];
    const void* effw1 = d_in[14];
    const void* effb1 = d_in[15];
    const void* effw2 = d_in[16];
    const void* effb2 = d_in[17];
    const void* eln1  = d_in[18];
    const void* eln2  = d_in[19];
    const void* cw    = d_in[20];
    const void* cb    = d_in[21];
    const void* cbn_g = d_in[22];
    const void* cbn_b = d_in[23];
    const void* enc_norm = d_in[24];
    const void* dsW   = d_in[25];
    const void* dsb   = d_in[26];
    const void* dcW   = d_in[27];
    const void* dcb   = d_in[28];
    const void* dffw1 = d_in[29];
    const void* dffb1 = d_in[30];
    const void* dffw2 = d_in[31];
    const void* dffb2 = d_in[32];
    const void* dln   = d_in[33];
    const void* dec_norm = d_in[34];
    const void* fcw   = d_in[35];
    const void* fcb   = d_in[36];

    // ---- workspace layout (33 MiB + 4 B) ----
    char* wsp = (char*)d_ws;
    bf16* X  = (bf16*)wsp;                            // 8 MiB
    bf16* Qb = (bf16*)(wsp + ((size_t)8 << 20));      // 8 MiB (conv scratch while Q dead)
    bf16* Kb = (bf16*)(wsp + ((size_t)16 << 20));     // 8 MiB
    bf16* VT = (bf16*)(wsp + ((size_t)24 << 20));     // 8.5 MiB (conv out 8.03 MiB)
    bf16*  WTCb = Qb;                                             // 1.5 MiB
    int*   IDX  = (int*)(wsp + ((size_t)8 << 20) + 1572864);      // 96 KiB
    float* PART = (float*)(wsp + ((size_t)8 << 20) + 1835008);    // 128 KiB
    float* STATS= (float*)(wsp + ((size_t)8 << 20) + 2097152);    // 4 KiB
    int*   FLAG = (int*)(wsp + ((size_t)33 << 20));
    bf16* MEMb = X;                                               // 16*130*512
    bf16* Yd   = (bf16*)(wsp + (size_t)16 * 130 * 512 * 2);       // 16*256*512

    auto cdiv = [](int a, int b) { return (a + b - 1) / b; };

    // dtype sniff on x_mark_enc (32768 elems -> 16384 words safe for both dtypes)
    sniff_k<<<1, 256, 0, stream>>>((const unsigned*)x_mark_enc, 16384, FLAG);

    // ---- encoder embedding ----
    embed_k<<<cdiv(16 * 512 * 512, 256), 256, 0, stream>>>(
        x_enc, enc_vw, enc_vb, x_mark_enc, enc_mw, enc_mb, X, 16 * 512, 7, 4, FLAG);

    // ---- encoder ----
    int L = 512;
    for (int i = 0; i < 3; ++i) {
        const int rows = 16 * L;
        const unsigned W0 = (unsigned)i * 4u * 262144u;
        const unsigned b0 = (unsigned)i * 4u * 512u;
        dim3 g8(8, cdiv(rows, 64));
        gemm_off_k<false><<<g8, 256, 0, stream>>>(X, eW, W0 + 0u * 262144u, ebi, b0 + 0u * 512u, Qb, rows, 512, 512, FLAG);
        gemm_off_k<false><<<g8, 256, 0, stream>>>(X, eW, W0 + 1u * 262144u, ebi, b0 + 1u * 512u, Kb, rows, 512, 512, FLAG);
        gemm_off_k<false><<<g8, 256, 0, stream>>>(X, eW, W0 + 2u * 262144u, ebi, b0 + 2u * 512u, VT, rows, 512, 512, FLAG);
        attn_k<true, false><<<dim3(L, 8, 16), 256, 0, stream>>>(Qb, Kb, VT, L, L);
        gemm_off_k<false><<<g8, 256, 0, stream>>>(Qb, eW, W0 + 3u * 262144u, ebi, b0 + 3u * 512u, Kb, rows, 512, 512, FLAG);
        ln_off_k<<<rows, 256, 0, stream>>>(X, Kb, eln1, (unsigned)i * 1024u, X, FLAG);
        for (int c0 = 0; c0 < rows; c0 += 2048) {
            const int mc = (rows - c0) < 2048 ? (rows - c0) : 2048;
            gemm_off_k<true><<<dim3(32, cdiv(mc, 64)), 256, 0, stream>>>(
                X + (size_t)c0 * 512, effw1, (unsigned)i * 1048576u, effb1, (unsigned)i * 2048u,
                VT, mc, 2048, 512, FLAG);
            gemm_off_k<false><<<dim3(8, cdiv(mc, 64)), 256, 0, stream>>>(
                VT, effw2, (unsigned)i * 1048576u, effb2, (unsigned)i * 512u,
                Kb + (size_t)c0 * 512, mc, 512, 2048, FLAG);
        }
        ln_off_k<<<rows, 256, 0, stream>>>(X, Kb, eln2, (unsigned)i * 1024u, X, FLAG);

        if (i < 2) {
            convw_k<<<cdiv(786432, 256), 256, 0, stream>>>(cw, (unsigned)i * 786432u, WTCb, 786432, FLAG);
            const int Lc = L + 2, Mc = 16 * Lc;
            convidx_k<<<cdiv(3 * Mc, 256), 256, 0, stream>>>(IDX, Lc, L, 3 * Mc);
            gemm3_k<<<dim3(8, cdiv(Mc, 64)), 256, 0, stream>>>(
                X, IDX, WTCb, cb, (unsigned)i * 512u, VT, Mc, 512, FLAG);
            bnstat1_k<<<32, 256, 0, stream>>>(VT, PART, Mc);
            bnstat2_k<<<2, 256, 0, stream>>>(PART, STATS, 32, Mc);
            const int Lout = (L + 1) / 2 + 1;   // 514->257, 259->130
            const int tot = 16 * Lout * 512;
            bnpool_k<<<cdiv(tot, 256), 256, 0, stream>>>(
                VT, STATS, cbn_g, cbn_b, (unsigned)i * 512u, X, Lc, Lout, tot, FLAG);
            L = Lout;
        }
    }
    const int Lm = L;  // 130
    ln_off_k<<<16 * Lm, 256, 0, stream>>>(X, nullptr, enc_norm, 0u, MEMb, FLAG);

    // ---- decoder embedding ----
    const int rowsD = 16 * 256;
    embed_k<<<cdiv(rowsD * 512, 256), 256, 0, stream>>>(
        x_dec, dec_vw, dec_vb, x_mark_dec, dec_mw, dec_mb, Yd, rowsD, 7, 4, FLAG);

    // ---- decoder ----
    for (int i = 0; i < 2; ++i) {
        const unsigned W0 = (unsigned)i * 4u * 262144u;
        const unsigned b0 = (unsigned)i * 4u * 512u;
        dim3 g8(8, cdiv(rowsD, 64));
        gemm_off_k<false><<<g8, 256, 0, stream>>>(Yd, dsW, W0 + 0u * 262144u, dsb, b0 + 0u * 512u, Qb, rowsD, 512, 512, FLAG);
        gemm_off_k<false><<<g8, 256, 0, stream>>>(Yd, dsW, W0 + 1u * 262144u, dsb, b0 + 1u * 512u, Kb, rowsD, 512, 512, FLAG);
        gemm_off_k<false><<<g8, 256, 0, stream>>>(Yd, dsW, W0 + 2u * 262144u, dsb, b0 + 2u * 512u, VT, rowsD, 512, 512, FLAG);
        attn_k<false, true><<<dim3(256, 8, 16), 256, 0, stream>>>(Qb, Kb, VT, 256, 256);
        gemm_off_k<false><<<g8, 256, 0, stream>>>(Qb, dsW, W0 + 3u * 262144u, dsb, b0 + 3u * 512u, Kb, rowsD, 512, 512, FLAG);
        ln_off_k<<<rowsD, 256, 0, stream>>>(Yd, Kb, dln, (unsigned)(i * 3 + 0) * 1024u, Yd, FLAG);

        dim3 gm(8, cdiv(16 * Lm, 64));
        gemm_off_k<false><<<g8, 256, 0, stream>>>(Yd,   dcW, W0 + 0u * 262144u, dcb, b0 + 0u * 512u, Qb, rowsD, 512, 512, FLAG);
        gemm_off_k<false><<<gm, 256, 0, stream>>>(MEMb, dcW, W0 + 1u * 262144u, dcb, b0 + 1u * 512u, Kb, 16 * Lm, 512, 512, FLAG);
        gemm_off_k<false><<<gm, 256, 0, stream>>>(MEMb, dcW, W0 + 2u * 262144u, dcb, b0 + 2u * 512u, VT, 16 * Lm, 512, 512, FLAG);
        attn_k<false, false><<<dim3(256, 8, 16), 256, 0, stream>>>(Qb, Kb, VT, 256, Lm);
        gemm_off_k<false><<<g8, 256, 0, stream>>>(Qb, dcW, W0 + 3u * 262144u, dcb, b0 + 3u * 512u, Kb, rowsD, 512, 512, FLAG);
        ln_off_k<<<rowsD, 256, 0, stream>>>(Yd, Kb, dln, (unsigned)(i * 3 + 1) * 1024u, Yd, FLAG);

        for (int c0 = 0; c0 < rowsD; c0 += 2048) {
            gemm_off_k<true><<<dim3(32, 32), 256, 0, stream>>>(
                Yd + (size_t)c0 * 512, dffw1, (unsigned)i * 1048576u, dffb1, (unsigned)i * 2048u,
                VT, 2048, 2048, 512, FLAG);
            gemm_off_k<false><<<dim3(8, 32), 256, 0, stream>>>(
                VT, dffw2, (unsigned)i * 1048576u, dffb2, (unsigned)i * 512u,
                Kb + (size_t)c0 * 512, 2048, 512, 2048, FLAG);
        }
        ln_off_k<<<rowsD, 256, 0, stream>>>(Yd, Kb, dln, (unsigned)(i * 3 + 2) * 1024u, Yd, FLAG);
    }

    ln_off_k<<<rowsD, 256, 0, stream>>>(Yd, nullptr, dec_norm, 0u, Qb, FLAG);
    fc_k<<<cdiv(rowsD * 7, 256), 256, 0, stream>>>(Qb, fcw, fcb, d_out, rowsD * 7, FLAG);
}

// Round 4
// 9941.373 us; speedup vs baseline: 1.2855x; 1.2855x over previous
//
#include <hip/hip_runtime.h>
#include <hip/hip_bf16.h>

// Informer forward, MI355X. Round 4: MFMA bf16 GEMMs (128x128 tile, BK=32,
// mfma_f32_16x16x32_bf16) with one-time transposed-weight staging; dtype sniffer
// and bf16 pipeline retained from round 3 (passed, absmax 0.0095).
// B=16, LE=512, LD=256, D=512, H=8, dk=64, DFF=2048, NE=3, ND=2, TOPK=16.
// Encoder lengths: 512 -> conv(514)/pool -> 257 -> conv(259)/pool -> 130.

#define DM 512
#define DK 64

using bf16 = __hip_bfloat16;
typedef short s8v __attribute__((ext_vector_type(8)));
typedef float f4v __attribute__((ext_vector_type(4)));

__device__ inline float b2f(bf16 x) { return __bfloat162float(x); }
__device__ inline float u2f(unsigned short u) { return __uint_as_float((unsigned)u << 16); }

// flag f: 1 = raw inputs are bf16, 0 = raw inputs are fp32. idx in ELEMENTS.
__device__ inline float ldw(const void* p, unsigned i, int f) {
    return f ? b2f(((const bf16*)p)[i]) : ((const float*)p)[i];
}

// ---------------- dtype sniffer ----------------
__global__ __launch_bounds__(256) void sniff_k(const unsigned* __restrict__ x, int nwords,
                                               int* __restrict__ flag) {
    __shared__ int red[4];
    const int t = threadIdx.x;
    int c = 0;
    for (int i = t; i < nwords; i += 256) c += ((x[i] & 0x7F80u) == 0x3F80u) ? 1 : 0;
    #pragma unroll
    for (int o = 32; o > 0; o >>= 1) c += __shfl_down(c, o);
    __syncthreads();
    if ((t & 63) == 0) red[t >> 6] = c;
    __syncthreads();
    if (t == 0) flag[0] = (red[0] + red[1] + red[2] + red[3] > nwords / 20) ? 1 : 0;
}

// ---------------- reductions (blockDim == 256) ----------------
__device__ inline float block_sum256(float v, float* red) {
    #pragma unroll
    for (int o = 32; o > 0; o >>= 1) v += __shfl_down(v, o);
    __syncthreads();
    if ((threadIdx.x & 63) == 0) red[threadIdx.x >> 6] = v;
    __syncthreads();
    return red[0] + red[1] + red[2] + red[3];
}
__device__ inline float block_max256(float v, float* red) {
    #pragma unroll
    for (int o = 32; o > 0; o >>= 1) v = fmaxf(v, __shfl_down(v, o));
    __syncthreads();
    if ((threadIdx.x & 63) == 0) red[threadIdx.x >> 6] = v;
    __syncthreads();
    return fmaxf(fmaxf(red[0], red[1]), fmaxf(red[2], red[3]));
}

// ---------------- embedding ----------------
__global__ __launch_bounds__(256) void embed_k(
    const void* __restrict__ xv, const void* __restrict__ vw, const void* __restrict__ vb,
    const void* __restrict__ xm, const void* __restrict__ mw, const void* __restrict__ mb,
    bf16* __restrict__ Out, int rows, int Cv, int Cm, const int* __restrict__ flagp)
{
    const int f = *flagp;
    int i = blockIdx.x * 256 + threadIdx.x;
    if (i >= rows * DM) return;
    const int r = i >> 9, d = i & 511;
    float acc = ldw(vb, d, f) + ldw(mb, d, f);
    for (int c = 0; c < Cv; ++c) acc += ldw(xv, r * Cv + c, f) * ldw(vw, c * DM + d, f);
    for (int c = 0; c < Cm; ++c) acc += ldw(xm, r * Cm + c, f) * ldw(mw, c * DM + d, f);
    Out[i] = __float2bfloat16(acc);
}

// ---------------- weight transpose: raw [K][N] (flag dtype) -> bf16 [N][K] ----------------
__global__ __launch_bounds__(256) void transp_k(
    const void* __restrict__ W, unsigned off, bf16* __restrict__ out,
    int K, int N, const int* __restrict__ flagp)
{
    __shared__ float tile[32][33];
    const int f = *flagp;
    const int t = threadIdx.x;
    const int tx = t & 31, ty = t >> 5;               // 32 x 8
    const int n0 = blockIdx.x * 32, k0 = blockIdx.y * 32;
    #pragma unroll
    for (int i = 0; i < 4; ++i)
        tile[ty + 8 * i][tx] = ldw(W, off + (unsigned)(k0 + ty + 8 * i) * N + n0 + tx, f);
    __syncthreads();
    #pragma unroll
    for (int i = 0; i < 4; ++i)
        out[(size_t)(n0 + ty + 8 * i) * K + k0 + tx] = __float2bfloat16(tile[tx][ty + 8 * i]);
}

// ---------------- MFMA GEMM: C[M,N] = A[M,K] @ Wt[N,K]^T + bias, opt ReLU ----------------
// A bf16 [M][K] (G3: 3-tap row gather, segment width 512); Wt bf16 [N][K] (pre-transposed).
// 128x128 tile, BK=32, 4 waves each computing a 64x64 quadrant via 4x4 mfma 16x16x32.
template<bool G3, bool RELU>
__global__ __launch_bounds__(256) void mgemm_k(
    const short* __restrict__ A, const int* __restrict__ ridx,
    const short* __restrict__ Wt,
    const void* __restrict__ bias, unsigned boff0,
    bf16* __restrict__ C, int M, int N, int K, const int* __restrict__ flagp)
{
    __shared__ short As[128 * 40];   // pitch 40 shorts (80 B): 16B-aligned frag reads
    __shared__ short Ws[128 * 40];
    const int t = threadIdx.x;
    const int bm = blockIdx.y * 128, bn = blockIdx.x * 128;
    const int lane = t & 63, wave = t >> 6;
    const int mbase = (wave >> 1) * 64, nbase = (wave & 1) * 64;
    const int l15 = lane & 15, quad = lane >> 4;

    const int sm0 = t >> 2;              // staging row 0 (0..63)
    const int skq = (t & 3) * 8;         // staging k-chunk offset {0,8,16,24}

    f4v acc[4][4] = {};

    for (int k0 = 0; k0 < K; k0 += 32) {
        __syncthreads();
        // ---- stage A (rows sm0, sm0+64) ----
        #pragma unroll
        for (int h = 0; h < 2; ++h) {
            const int m = sm0 + h * 64;
            const int row = bm + m;
            size_t off;
            if (G3) {
                const int seg = k0 >> 9;
                const int r = (row < M) ? ridx[seg * M + row] : 0;
                off = (size_t)r * 512 + (k0 & 511) + skq;
            } else {
                const int rowc = row < M ? row : (M - 1);
                off = (size_t)rowc * K + k0 + skq;
            }
            *(s8v*)&As[m * 40 + skq] = *(const s8v*)(A + off);
        }
        // ---- stage Wt (rows bn+sm0, bn+sm0+64; N multiple of 128) ----
        #pragma unroll
        for (int h = 0; h < 2; ++h) {
            const int n = sm0 + h * 64;
            *(s8v*)&Ws[n * 40 + skq] = *(const s8v*)(Wt + (size_t)(bn + n) * K + k0 + skq);
        }
        __syncthreads();
        // ---- fragments + 16 MFMA ----
        s8v af[4], bfv[4];
        #pragma unroll
        for (int i = 0; i < 4; ++i) {
            af[i]  = *(const s8v*)&As[(mbase + i * 16 + l15) * 40 + quad * 8];
            bfv[i] = *(const s8v*)&Ws[(nbase + i * 16 + l15) * 40 + quad * 8];
        }
        #pragma unroll
        for (int mi = 0; mi < 4; ++mi)
            #pragma unroll
            for (int ni = 0; ni < 4; ++ni)
                acc[mi][ni] = __builtin_amdgcn_mfma_f32_16x16x32_bf16(
                    af[mi], bfv[ni], acc[mi][ni], 0, 0, 0);
    }

    const int f = *flagp;
    float bv[4];
    #pragma unroll
    for (int ni = 0; ni < 4; ++ni)
        bv[ni] = ldw(bias, boff0 + (unsigned)(bn + nbase + ni * 16 + l15), f);

    #pragma unroll
    for (int mi = 0; mi < 4; ++mi) {
        #pragma unroll
        for (int r = 0; r < 4; ++r) {
            const int row = bm + mbase + mi * 16 + quad * 4 + r;
            if (row < M) {
                #pragma unroll
                for (int ni = 0; ni < 4; ++ni) {
                    float o = acc[mi][ni][r] + bv[ni];
                    if (RELU) o = fmaxf(o, 0.f);
                    C[(size_t)row * N + bn + nbase + ni * 16 + l15] = __float2bfloat16(o);
                }
            }
        }
    }
}

// ---------------- attention: one block per (b,h,q); O written in-place over Q ----------------
template<bool TOPK_ON, bool CAUSAL>
__global__ __launch_bounds__(256) void attn_k(
    bf16* __restrict__ Q, const bf16* __restrict__ Kv,
    const bf16* __restrict__ Vv, int Lq, int Lk)
{
    __shared__ float qs[DK];
    __shared__ float s[512];
    __shared__ float sc[TOPK_ON ? 512 : 1];
    __shared__ float part[4][DK];
    __shared__ float red[4];
    __shared__ int   redi[4];
    __shared__ float bcast[1];

    const int t = threadIdx.x;
    const int q = blockIdx.x, h = blockIdx.y, b = blockIdx.z;

    bf16* Qp = Q + ((size_t)b * Lq + q) * DM + h * DK;
    if (t < DK) qs[t] = b2f(Qp[t]);
    __syncthreads();

    for (int k = t; k < Lk; k += 256) {
        const bf16* Kp = Kv + ((size_t)b * Lk + k) * DM + h * DK;
        float acc = 0.f;
        #pragma unroll
        for (int d = 0; d < DK; d += 4) {
            const ushort4 kv = *reinterpret_cast<const ushort4*>(Kp + d);
            acc += qs[d] * u2f(kv.x) + qs[d + 1] * u2f(kv.y)
                 + qs[d + 2] * u2f(kv.z) + qs[d + 3] * u2f(kv.w);
        }
        acc *= 0.125f;  // 1/sqrt(64)
        if (CAUSAL && k > q) acc -= 1e9f;
        s[k] = acc;
        if (TOPK_ON) sc[k] = acc;
    }
    __syncthreads();

    float m, kth = 0.f;
    if (TOPK_ON) {
        float mx0 = 0.f, last = 0.f;
        for (int it = 0; it < 16; ++it) {
            float lv = -INFINITY; int li = 0;
            for (int k = t; k < Lk; k += 256)
                if (sc[k] > lv) { lv = sc[k]; li = k; }
            #pragma unroll
            for (int o = 32; o > 0; o >>= 1) {
                const float ov = __shfl_down(lv, o);
                const int   oi = __shfl_down(li, o);
                if (ov > lv) { lv = ov; li = oi; }
            }
            if ((t & 63) == 0) { red[t >> 6] = lv; redi[t >> 6] = li; }
            __syncthreads();
            if (t == 0) {
                float bvv = red[0]; int bi = redi[0];
                #pragma unroll
                for (int w = 1; w < 4; ++w)
                    if (red[w] > bvv) { bvv = red[w]; bi = redi[w]; }
                sc[bi] = -INFINITY;
                bcast[0] = bvv;
            }
            __syncthreads();
            const float bvv = bcast[0];
            if (it == 0) mx0 = bvv;
            last = bvv;
        }
        m = mx0; kth = last;
    } else {
        float lv = -INFINITY;
        for (int k = t; k < Lk; k += 256) lv = fmaxf(lv, s[k]);
        m = block_max256(lv, red);
    }

    float dpart = 0.f;
    for (int k = t; k < Lk; k += 256) {
        const float sv = s[k];
        float w;
        if (TOPK_ON) w = (sv >= kth) ? expf(sv - m) : 0.f;
        else         w = expf(sv - m);
        s[k] = w;
        dpart += w;
    }
    const float denom = block_sum256(dpart, red);
    const float inv = 1.f / denom;

    const int dd = t & 63, kc = t >> 6;
    float accv = 0.f;
    for (int k = kc; k < Lk; k += 4) {
        const float w = s[k];
        if (w != 0.f)
            accv += w * b2f(Vv[((size_t)b * Lk + k) * DM + h * DK + dd]);
    }
    part[kc][dd] = accv;
    __syncthreads();
    if (t < DK)
        Qp[t] = __float2bfloat16((part[0][t] + part[1][t] + part[2][t] + part[3][t]) * inv);
}

// ---------------- layernorm over D=512, optional residual; in-place safe ----------------
__global__ __launch_bounds__(256) void ln_off_k(
    const bf16* __restrict__ X, const bf16* __restrict__ R,
    const void* __restrict__ gb, unsigned goff,
    bf16* __restrict__ Out, const int* __restrict__ flagp)
{
    __shared__ float red[4];
    const int f = *flagp;
    const int t = threadIdx.x;
    const size_t base = (size_t)blockIdx.x * DM;
    float v0 = b2f(X[base + t]), v1 = b2f(X[base + t + 256]);
    if (R) { v0 += b2f(R[base + t]); v1 += b2f(R[base + t + 256]); }
    const float mean = block_sum256(v0 + v1, red) * (1.f / 512.f);
    const float d0 = v0 - mean, d1 = v1 - mean;
    const float var = block_sum256(d0 * d0 + d1 * d1, red) * (1.f / 512.f);
    const float rstd = rsqrtf(var + 1e-5f);
    Out[base + t]       = __float2bfloat16(d0 * rstd * ldw(gb, goff + t, f)       + ldw(gb, goff + 512 + t, f));
    Out[base + t + 256] = __float2bfloat16(d1 * rstd * ldw(gb, goff + t + 256, f) + ldw(gb, goff + 768 + t, f));
}

// ---------------- conv distill helpers ----------------
// conv weights w[o][c][j] (512,512,3) -> transposed GEMM layout wt[o][j*512+c] ([N=512][K=1536])
__global__ __launch_bounds__(256) void convw_k(const void* __restrict__ w, unsigned woff,
                                               bf16* __restrict__ wt, int total,
                                               const int* __restrict__ flagp) {
    const int f = *flagp;
    int i = blockIdx.x * 256 + threadIdx.x;
    if (i >= total) return;
    const int o = i / 1536, rem = i % 1536;
    const int j = rem >> 9, c = rem & 511;
    wt[i] = __float2bfloat16(ldw(w, woff + (unsigned)(o * 512 + c) * 3 + j, f));
}

__global__ __launch_bounds__(256) void convidx_k(int* __restrict__ idx, int Lc, int L, int total) {
    int i = blockIdx.x * 256 + threadIdx.x;
    if (i >= total) return;
    const int j = i / (16 * Lc), mrem = i % (16 * Lc);
    const int b = mrem / Lc, l = mrem % Lc;
    int src = l + j - 2;
    src %= L; if (src < 0) src += L;
    idx[i] = b * L + src;
}

__global__ __launch_bounds__(256) void bnstat1_k(const bf16* __restrict__ Y, float* __restrict__ part, int M) {
    const int t = threadIdx.x;
    float s0 = 0.f, q0 = 0.f, s1 = 0.f, q1 = 0.f;
    for (int r = blockIdx.x; r < M; r += gridDim.x) {
        const ushort2 u = *reinterpret_cast<const ushort2*>(Y + (size_t)r * DM + t * 2);
        const float a = u2f(u.x), c = u2f(u.y);
        s0 += a; q0 += a * a;
        s1 += c; q1 += c * c;
    }
    float* p = part + (size_t)blockIdx.x * 1024;
    p[2 * t] = s0; p[2 * t + 1] = s1;
    p[512 + 2 * t] = q0; p[512 + 2 * t + 1] = q1;
}

__global__ __launch_bounds__(256) void bnstat2_k(const float* __restrict__ part, float* __restrict__ stats,
                                                 int nchunk, int M) {
    const int ch = blockIdx.x * 256 + threadIdx.x;
    if (ch >= 512) return;
    float S = 0.f, Qs = 0.f;
    for (int c = 0; c < nchunk; ++c) { S += part[c * 1024 + ch]; Qs += part[c * 1024 + 512 + ch]; }
    const float mean = S / (float)M;
    const float var = Qs / (float)M - mean * mean;
    stats[ch] = mean;
    stats[512 + ch] = fmaxf(var, 0.f);
}

__global__ __launch_bounds__(256) void bnpool_k(
    const bf16* __restrict__ Yc, const float* __restrict__ stats,
    const void* __restrict__ g, const void* __restrict__ bb, unsigned off,
    bf16* __restrict__ Out, int Lc, int Lout, int total, const int* __restrict__ flagp)
{
    const int f = *flagp;
    int i = blockIdx.x * 256 + threadIdx.x;
    if (i >= total) return;
    const int ch = i & 511;
    const int lp = (i >> 9) % Lout;
    const int b = i / (512 * Lout);
    const float mean = stats[ch], var = stats[512 + ch];
    const float sc = ldw(g, off + ch, f) * rsqrtf(var + 1e-5f);
    const float sh = ldw(bb, off + ch, f) - mean * sc;
    float mx = -INFINITY;
    const int l0 = 2 * lp - 1;
    #pragma unroll
    for (int d = 0; d < 3; ++d) {
        const int l = l0 + d;
        if (l >= 0 && l < Lc) {
            float v = b2f(Yc[((size_t)b * Lc + l) * DM + ch]) * sc + sh;
            v = v > 0.f ? v : expm1f(v);  // ELU
            mx = fmaxf(mx, v);
        }
    }
    Out[((size_t)b * Lout + lp) * DM + ch] = __float2bfloat16(mx);
}

// ---------------- final projection to CO=7, dtype-matched store ----------------
__global__ __launch_bounds__(256) void fc_k(
    const bf16* __restrict__ Yn, const void* __restrict__ fcw, const void* __restrict__ fcb,
    void* __restrict__ out, int total, const int* __restrict__ flagp)
{
    const int f = *flagp;
    int i = blockIdx.x * 256 + threadIdx.x;
    if (i >= total) return;
    const int r = i / 7, co = i % 7;
    const bf16* yr = Yn + (size_t)r * DM;
    float acc = ldw(fcb, co, f);
    for (int d = 0; d < DM; ++d) acc += b2f(yr[d]) * ldw(fcw, d * 7 + co, f);
    if (f) ((bf16*)out)[i] = __float2bfloat16(acc);
    else   ((float*)out)[i] = acc;
}

// =============================================================================
extern "C" void kernel_launch(void* const* d_in, const int* in_sizes, int n_in,
                              void* d_out, int out_size, void* d_ws, size_t ws_size,
                              hipStream_t stream)
{
    const void* x_enc      = d_in[0];
    const void* x_mark_enc = d_in[1];
    const void* x_dec      = d_in[2];
    const void* x_mark_dec = d_in[3];
    const void* enc_vw = d_in[4];
    const void* enc_vb = d_in[5];
    const void* enc_mw = d_in[6];
    const void* enc_mb = d_in[7];
    const void* dec_vw = d_in[8];
    const void* dec_vb = d_in[9];
    const void* dec_mw = d_in[10];
    const void* dec_mb = d_in[11];
    const void* eW    = d_in[12];
    const void* ebi   = d_in[13];
    const void* effw1 = d_in[14];
    const void* effb1 = d_in[15];
    const void* effw2 = d_in[16];
    const void* effb2 = d_in[17];
    const void* eln1  = d_in[18];
    const void* eln2  = d_in[19];
    const void* cw    = d_in[20];
    const void* cb    = d_in[21];
    const void* cbn_g = d_in[22];
    const void* cbn_b = d_in[23];
    const void* enc_norm = d_in[24];
    const void* dsW   = d_in[25];
    const void* dsb   = d_in[26];
    const void* dcW   = d_in[27];
    const void* dcb   = d_in[28];
    const void* dffw1 = d_in[29];
    const void* dffb1 = d_in[30];
    const void* dffw2 = d_in[31];
    const void* dffb2 = d_in[32];
    const void* dln   = d_in[33];
    const void* dec_norm = d_in[34];
    const void* fcw   = d_in[35];
    const void* fcb   = d_in[36];

    // ---- workspace layout (~36.5 MiB + 4 B) ----
    // X[0,8M) | Qb[8M,16M) (conv scratch while Q dead) | Kb[16M,24M) | VT[24M,32.5M)
    // WT arena [32.5M, 36.5M) | FLAG @ 36.5M
    char* wsp = (char*)d_ws;
    bf16* X  = (bf16*)wsp;
    bf16* Qb = (bf16*)(wsp + ((size_t)8 << 20));
    bf16* Kb = (bf16*)(wsp + ((size_t)16 << 20));
    bf16* VT = (bf16*)(wsp + ((size_t)24 << 20));
    bf16*  WTCb = Qb;                                             // conv Wt [512][1536], 1.5 MiB
    int*   IDX  = (int*)(wsp + ((size_t)8 << 20) + 1572864);
    float* PART = (float*)(wsp + ((size_t)8 << 20) + 1835008);
    float* STATS= (float*)(wsp + ((size_t)8 << 20) + 2097152);
    bf16* WT   = (bf16*)(wsp + ((size_t)32 << 20) + ((size_t)1 << 19));   // 4 MiB arena
    int*  FLAG = (int*)(wsp + ((size_t)36 << 20) + ((size_t)1 << 19));
    bf16* MEMb = X;
    bf16* Yd   = (bf16*)(wsp + (size_t)16 * 130 * 512 * 2);

    // arena slots (element offsets): 4x 512x512 mats, or w1t(1M)+w2t(1M)
    bf16* TS[4] = { WT, WT + 262144, WT + 524288, WT + 786432 };
    bf16* W1T = WT;
    bf16* W2T = WT + 1048576;

    auto cdiv = [](int a, int b) { return (a + b - 1) / b; };
    auto transp = [&](const void* W, unsigned off, bf16* out, int K, int N) {
        transp_k<<<dim3(N / 32, K / 32), 256, 0, stream>>>(W, off, out, K, N, FLAG);
    };
    auto mgemm = [&](const bf16* A, const bf16* Wt, const void* bias, unsigned boff,
                     bf16* C, int M, int N, int K, bool relu) {
        dim3 g(N / 128, cdiv(M, 128));
        if (relu) mgemm_k<false, true><<<g, 256, 0, stream>>>(
            (const short*)A, nullptr, (const short*)Wt, bias, boff, C, M, N, K, FLAG);
        else      mgemm_k<false, false><<<g, 256, 0, stream>>>(
            (const short*)A, nullptr, (const short*)Wt, bias, boff, C, M, N, K, FLAG);
    };

    // dtype sniff on x_mark_enc (32768 elems -> 16384 words safe for both dtypes)
    sniff_k<<<1, 256, 0, stream>>>((const unsigned*)x_mark_enc, 16384, FLAG);

    // ---- encoder embedding ----
    embed_k<<<cdiv(16 * 512 * 512, 256), 256, 0, stream>>>(
        x_enc, enc_vw, enc_vb, x_mark_enc, enc_mw, enc_mb, X, 16 * 512, 7, 4, FLAG);

    // ---- encoder ----
    int L = 512;
    for (int i = 0; i < 3; ++i) {
        const int rows = 16 * L;
        const unsigned W0 = (unsigned)i * 4u * 262144u;
        const unsigned b0 = (unsigned)i * 4u * 512u;
        for (int q = 0; q < 4; ++q) transp(eW, W0 + q * 262144u, TS[q], 512, 512);
        mgemm(X, TS[0], ebi, b0 + 0u * 512u, Qb, rows, 512, 512, false);
        mgemm(X, TS[1], ebi, b0 + 1u * 512u, Kb, rows, 512, 512, false);
        mgemm(X, TS[2], ebi, b0 + 2u * 512u, VT, rows, 512, 512, false);
        attn_k<true, false><<<dim3(L, 8, 16), 256, 0, stream>>>(Qb, Kb, VT, L, L);
        mgemm(Qb, TS[3], ebi, b0 + 3u * 512u, Kb, rows, 512, 512, false);
        ln_off_k<<<rows, 256, 0, stream>>>(X, Kb, eln1, (unsigned)i * 1024u, X, FLAG);

        transp(effw1, (unsigned)i * 1048576u, W1T, 512, 2048);
        transp(effw2, (unsigned)i * 1048576u, W2T, 2048, 512);
        for (int c0 = 0; c0 < rows; c0 += 2048) {
            const int mc = (rows - c0) < 2048 ? (rows - c0) : 2048;
            mgemm(X + (size_t)c0 * 512, W1T, effb1, (unsigned)i * 2048u, VT, mc, 2048, 512, true);
            mgemm(VT, W2T, effb2, (unsigned)i * 512u, Kb + (size_t)c0 * 512, mc, 512, 2048, false);
        }
        ln_off_k<<<rows, 256, 0, stream>>>(X, Kb, eln2, (unsigned)i * 1024u, X, FLAG);

        if (i < 2) {
            convw_k<<<cdiv(786432, 256), 256, 0, stream>>>(cw, (unsigned)i * 786432u, WTCb, 786432, FLAG);
            const int Lc = L + 2, Mc = 16 * Lc;
            convidx_k<<<cdiv(3 * Mc, 256), 256, 0, stream>>>(IDX, Lc, L, 3 * Mc);
            mgemm_k<true, false><<<dim3(4, cdiv(Mc, 128)), 256, 0, stream>>>(
                (const short*)X, IDX, (const short*)WTCb, cb, (unsigned)i * 512u,
                VT, Mc, 512, 1536, FLAG);
            bnstat1_k<<<32, 256, 0, stream>>>(VT, PART, Mc);
            bnstat2_k<<<2, 256, 0, stream>>>(PART, STATS, 32, Mc);
            const int Lout = (L + 1) / 2 + 1;   // 514->257, 259->130
            const int tot = 16 * Lout * 512;
            bnpool_k<<<cdiv(tot, 256), 256, 0, stream>>>(
                VT, STATS, cbn_g, cbn_b, (unsigned)i * 512u, X, Lc, Lout, tot, FLAG);
            L = Lout;
        }
    }
    const int Lm = L;  // 130
    ln_off_k<<<16 * Lm, 256, 0, stream>>>(X, nullptr, enc_norm, 0u, MEMb, FLAG);

    // ---- decoder embedding ----
    const int rowsD = 16 * 256;
    embed_k<<<cdiv(rowsD * 512, 256), 256, 0, stream>>>(
        x_dec, dec_vw, dec_vb, x_mark_dec, dec_mw, dec_mb, Yd, rowsD, 7, 4, FLAG);

    // ---- decoder ----
    for (int i = 0; i < 2; ++i) {
        const unsigned W0 = (unsigned)i * 4u * 262144u;
        const unsigned b0 = (unsigned)i * 4u * 512u;
        for (int q = 0; q < 4; ++q) transp(dsW, W0 + q * 262144u, TS[q], 512, 512);
        mgemm(Yd, TS[0], dsb, b0 + 0u * 512u, Qb, rowsD, 512, 512, false);
        mgemm(Yd, TS[1], dsb, b0 + 1u * 512u, Kb, rowsD, 512, 512, false);
        mgemm(Yd, TS[2], dsb, b0 + 2u * 512u, VT, rowsD, 512, 512, false);
        attn_k<false, true><<<dim3(256, 8, 16), 256, 0, stream>>>(Qb, Kb, VT, 256, 256);
        mgemm(Qb, TS[3], dsb, b0 + 3u * 512u, Kb, rowsD, 512, 512, false);
        ln_off_k<<<rowsD, 256, 0, stream>>>(Yd, Kb, dln, (unsigned)(i * 3 + 0) * 1024u, Yd, FLAG);

        for (int q = 0; q < 4; ++q) transp(dcW, W0 + q * 262144u, TS[q], 512, 512);
        mgemm(Yd,   TS[0], dcb, b0 + 0u * 512u, Qb, rowsD, 512, 512, false);
        mgemm(MEMb, TS[1], dcb, b0 + 1u * 512u, Kb, 16 * Lm, 512, 512, false);
        mgemm(MEMb, TS[2], dcb, b0 + 2u * 512u, VT, 16 * Lm, 512, 512, false);
        attn_k<false, false><<<dim3(256, 8, 16), 256, 0, stream>>>(Qb, Kb, VT, 256, Lm);
        mgemm(Qb, TS[3], dcb, b0 + 3u * 512u, Kb, rowsD, 512, 512, false);
        ln_off_k<<<rowsD, 256, 0, stream>>>(Yd, Kb, dln, (unsigned)(i * 3 + 1) * 1024u, Yd, FLAG);

        transp(dffw1, (unsigned)i * 1048576u, W1T, 512, 2048);
        transp(dffw2, (unsigned)i * 1048576u, W2T, 2048, 512);
        for (int c0 = 0; c0 < rowsD; c0 += 2048) {
            mgemm(Yd + (size_t)c0 * 512, W1T, dffb1, (unsigned)i * 2048u, VT, 2048, 2048, 512, true);
            mgemm(VT, W2T, dffb2, (unsigned)i * 512u, Kb + (size_t)c0 * 512, 2048, 512, 2048, false);
        }
        ln_off_k<<<rowsD, 256, 0, stream>>>(Yd, Kb, dln, (unsigned)(i * 3 + 2) * 1024u, Yd, FLAG);
    }

    ln_off_k<<<rowsD, 256, 0, stream>>>(Yd, nullptr, dec_norm, 0u, Qb, FLAG);
    fc_k<<<cdiv(rowsD * 7, 256), 256, 0, stream>>>(Qb, fcw, fcb, d_out, rowsD * 7, FLAG);
}

// Round 5
// 2747.488 us; speedup vs baseline: 4.6516x; 3.6183x over previous
//
#include <hip/hip_runtime.h>
#include <hip/hip_bf16.h>

// Informer forward, MI355X. Round 5: fused tile attention (MFMA QK^T, wave-local
// top-16, sparse PV for ProbSparse; dense scalar PV for decoder). MFMA GEMMs,
// dtype sniffer, bf16 pipeline retained from round 4 (passed, absmax 0.0117).
// B=16, LE=512, LD=256, D=512, H=8, dk=64, DFF=2048, NE=3, ND=2, TOPK=16.
// Encoder lengths: 512 -> conv(514)/pool -> 257 -> conv(259)/pool -> 130.

#define DM 512
#define DK 64

using bf16 = __hip_bfloat16;
typedef short s8v __attribute__((ext_vector_type(8)));
typedef float f4v __attribute__((ext_vector_type(4)));

__device__ inline float b2f(bf16 x) { return __bfloat162float(x); }
__device__ inline float u2f(unsigned short u) { return __uint_as_float((unsigned)u << 16); }

// flag f: 1 = raw inputs are bf16, 0 = raw inputs are fp32. idx in ELEMENTS.
__device__ inline float ldw(const void* p, unsigned i, int f) {
    return f ? b2f(((const bf16*)p)[i]) : ((const float*)p)[i];
}

// ---------------- dtype sniffer ----------------
__global__ __launch_bounds__(256) void sniff_k(const unsigned* __restrict__ x, int nwords,
                                               int* __restrict__ flag) {
    __shared__ int red[4];
    const int t = threadIdx.x;
    int c = 0;
    for (int i = t; i < nwords; i += 256) c += ((x[i] & 0x7F80u) == 0x3F80u) ? 1 : 0;
    #pragma unroll
    for (int o = 32; o > 0; o >>= 1) c += __shfl_down(c, o);
    __syncthreads();
    if ((t & 63) == 0) red[t >> 6] = c;
    __syncthreads();
    if (t == 0) flag[0] = (red[0] + red[1] + red[2] + red[3] > nwords / 20) ? 1 : 0;
}

// ---------------- reductions (blockDim == 256) ----------------
__device__ inline float block_sum256(float v, float* red) {
    #pragma unroll
    for (int o = 32; o > 0; o >>= 1) v += __shfl_down(v, o);
    __syncthreads();
    if ((threadIdx.x & 63) == 0) red[threadIdx.x >> 6] = v;
    __syncthreads();
    return red[0] + red[1] + red[2] + red[3];
}

// ---------------- embedding ----------------
__global__ __launch_bounds__(256) void embed_k(
    const void* __restrict__ xv, const void* __restrict__ vw, const void* __restrict__ vb,
    const void* __restrict__ xm, const void* __restrict__ mw, const void* __restrict__ mb,
    bf16* __restrict__ Out, int rows, int Cv, int Cm, const int* __restrict__ flagp)
{
    const int f = *flagp;
    int i = blockIdx.x * 256 + threadIdx.x;
    if (i >= rows * DM) return;
    const int r = i >> 9, d = i & 511;
    float acc = ldw(vb, d, f) + ldw(mb, d, f);
    for (int c = 0; c < Cv; ++c) acc += ldw(xv, r * Cv + c, f) * ldw(vw, c * DM + d, f);
    for (int c = 0; c < Cm; ++c) acc += ldw(xm, r * Cm + c, f) * ldw(mw, c * DM + d, f);
    Out[i] = __float2bfloat16(acc);
}

// ---------------- weight transpose: raw [K][N] (flag dtype) -> bf16 [N][K] ----------------
__global__ __launch_bounds__(256) void transp_k(
    const void* __restrict__ W, unsigned off, bf16* __restrict__ out,
    int K, int N, const int* __restrict__ flagp)
{
    __shared__ float tile[32][33];
    const int f = *flagp;
    const int t = threadIdx.x;
    const int tx = t & 31, ty = t >> 5;               // 32 x 8
    const int n0 = blockIdx.x * 32, k0 = blockIdx.y * 32;
    #pragma unroll
    for (int i = 0; i < 4; ++i)
        tile[ty + 8 * i][tx] = ldw(W, off + (unsigned)(k0 + ty + 8 * i) * N + n0 + tx, f);
    __syncthreads();
    #pragma unroll
    for (int i = 0; i < 4; ++i)
        out[(size_t)(n0 + ty + 8 * i) * K + k0 + tx] = __float2bfloat16(tile[tx][ty + 8 * i]);
}

// ---------------- MFMA GEMM: C[M,N] = A[M,K] @ Wt[N,K]^T + bias, opt ReLU ----------------
template<bool G3, bool RELU>
__global__ __launch_bounds__(256) void mgemm_k(
    const short* __restrict__ A, const int* __restrict__ ridx,
    const short* __restrict__ Wt,
    const void* __restrict__ bias, unsigned boff0,
    bf16* __restrict__ C, int M, int N, int K, const int* __restrict__ flagp)
{
    __shared__ short As[128 * 40];   // pitch 40 shorts (80 B): 16B-aligned frag reads
    __shared__ short Ws[128 * 40];
    const int t = threadIdx.x;
    const int bm = blockIdx.y * 128, bn = blockIdx.x * 128;
    const int lane = t & 63, wave = t >> 6;
    const int mbase = (wave >> 1) * 64, nbase = (wave & 1) * 64;
    const int l15 = lane & 15, quad = lane >> 4;

    const int sm0 = t >> 2;              // staging row 0 (0..63)
    const int skq = (t & 3) * 8;         // staging k-chunk offset {0,8,16,24}

    f4v acc[4][4] = {};

    for (int k0 = 0; k0 < K; k0 += 32) {
        __syncthreads();
        #pragma unroll
        for (int h = 0; h < 2; ++h) {
            const int m = sm0 + h * 64;
            const int row = bm + m;
            size_t off;
            if (G3) {
                const int seg = k0 >> 9;
                const int r = (row < M) ? ridx[seg * M + row] : 0;
                off = (size_t)r * 512 + (k0 & 511) + skq;
            } else {
                const int rowc = row < M ? row : (M - 1);
                off = (size_t)rowc * K + k0 + skq;
            }
            *(s8v*)&As[m * 40 + skq] = *(const s8v*)(A + off);
        }
        #pragma unroll
        for (int h = 0; h < 2; ++h) {
            const int n = sm0 + h * 64;
            *(s8v*)&Ws[n * 40 + skq] = *(const s8v*)(Wt + (size_t)(bn + n) * K + k0 + skq);
        }
        __syncthreads();
        s8v af[4], bfv[4];
        #pragma unroll
        for (int i = 0; i < 4; ++i) {
            af[i]  = *(const s8v*)&As[(mbase + i * 16 + l15) * 40 + quad * 8];
            bfv[i] = *(const s8v*)&Ws[(nbase + i * 16 + l15) * 40 + quad * 8];
        }
        #pragma unroll
        for (int mi = 0; mi < 4; ++mi)
            #pragma unroll
            for (int ni = 0; ni < 4; ++ni)
                acc[mi][ni] = __builtin_amdgcn_mfma_f32_16x16x32_bf16(
                    af[mi], bfv[ni], acc[mi][ni], 0, 0, 0);
    }

    const int f = *flagp;
    float bv[4];
    #pragma unroll
    for (int ni = 0; ni < 4; ++ni)
        bv[ni] = ldw(bias, boff0 + (unsigned)(bn + nbase + ni * 16 + l15), f);

    #pragma unroll
    for (int mi = 0; mi < 4; ++mi) {
        #pragma unroll
        for (int r = 0; r < 4; ++r) {
            const int row = bm + mbase + mi * 16 + quad * 4 + r;
            if (row < M) {
                #pragma unroll
                for (int ni = 0; ni < 4; ++ni) {
                    float o = acc[mi][ni][r] + bv[ni];
                    if (RELU) o = fmaxf(o, 0.f);
                    C[(size_t)row * N + bn + nbase + ni * 16 + l15] = __float2bfloat16(o);
                }
            }
        }
    }
}

// ---------------- fused tile attention ----------------
// MODE 0: ProbSparse top-16 (encoder). MODE 1: causal (decoder self). MODE 2: plain (cross).
// Block = 256 threads, one (b, h, 16-query tile). O overwrites Q in place.
template<int MODE>
__global__ __launch_bounds__(256) void fattn_k(
    bf16* __restrict__ Q, const bf16* __restrict__ Kv, const bf16* __restrict__ Vv,
    int Lq, int Lk)
{
    __shared__ short Qs[16 * 72];
    __shared__ short Ks[64 * 72];
    __shared__ float S[16 * 516];
    __shared__ float pw[16][16];
    __shared__ int   pidx[16][16];
    __shared__ float mrow[16];
    __shared__ float dinv[16];

    const int t = threadIdx.x;
    const int q0 = blockIdx.x * 16, h = blockIdx.y, b = blockIdx.z;
    const int lane = t & 63, wave = t >> 6;
    const int l15 = lane & 15, quad = lane >> 4;

    const bf16* Kbase = Kv + ((size_t)b * Lk) * DM + h * DK;
    const bf16* Vbase = Vv + ((size_t)b * Lk) * DM + h * DK;
    bf16* Qbase = Q + ((size_t)(b * Lq + q0)) * DM + h * DK;

    const int kmax = (MODE == 1) ? (q0 + 16 < Lk ? q0 + 16 : Lk) : Lk;
    const int ntile = (kmax + 63) >> 6;
    const int kpad = ntile << 6;

    // stage Q tile (16 x 64)
    if (t < 128)
        *(s8v*)&Qs[(t >> 3) * 72 + (t & 7) * 8] =
            *(const s8v*)(Qbase + (size_t)(t >> 3) * DM + (t & 7) * 8);

    // ---- phase 1: S = QK^T / 8 (+ masks), via MFMA ----
    for (int kt = 0; kt < ntile; ++kt) {
        __syncthreads();   // Qs ready (first iter) / Ks consumers done (later iters)
        const int k0 = kt << 6;
        int srow = k0 + (t >> 2); if (srow >= Lk) srow = Lk - 1;
        const bf16* kp = Kbase + (size_t)srow * DM + (t & 3) * 16;
        *(s8v*)&Ks[(t >> 2) * 72 + (t & 3) * 16]     = *(const s8v*)kp;
        *(s8v*)&Ks[(t >> 2) * 72 + (t & 3) * 16 + 8] = *(const s8v*)(kp + 8);
        __syncthreads();
        const s8v a0 = *(const s8v*)&Qs[l15 * 72 + quad * 8];
        const s8v a1 = *(const s8v*)&Qs[l15 * 72 + 32 + quad * 8];
        const s8v b0 = *(const s8v*)&Ks[(wave * 16 + l15) * 72 + quad * 8];
        const s8v b1 = *(const s8v*)&Ks[(wave * 16 + l15) * 72 + 32 + quad * 8];
        f4v acc = {0.f, 0.f, 0.f, 0.f};
        acc = __builtin_amdgcn_mfma_f32_16x16x32_bf16(a0, b0, acc, 0, 0, 0);
        acc = __builtin_amdgcn_mfma_f32_16x16x32_bf16(a1, b1, acc, 0, 0, 0);
        const int colg = k0 + wave * 16 + l15;
        #pragma unroll
        for (int r = 0; r < 4; ++r) {
            const int qrow = quad * 4 + r;
            float s = acc[r] * 0.125f;
            if (colg >= Lk) s = -1e9f;
            if (MODE == 1 && colg > q0 + qrow) s = -1e9f;
            S[qrow * 516 + colg] = s;
        }
    }
    __syncthreads();

    // ---- phase 2: per-row top-16 (MODE 0) or row max (MODE 1/2), wave-local ----
    #pragma unroll
    for (int r4 = 0; r4 < 4; ++r4) {
        const int row = wave * 4 + r4;
        float v[8];
        #pragma unroll
        for (int j = 0; j < 8; ++j) {
            const int col = lane + 64 * j;
            v[j] = (col < kpad) ? S[row * 516 + col] : -INFINITY;
        }
        if (MODE == 0) {
            unsigned used = 0;
            float denom = 0.f, m = 0.f;
            for (int it = 0; it < 16; ++it) {
                float lv = -INFINITY; int lj = 0;
                #pragma unroll
                for (int j = 0; j < 8; ++j) {
                    const float cand = (used >> j & 1u) ? -INFINITY : v[j];
                    if (cand > lv) { lv = cand; lj = j; }
                }
                int gcol = lane + 64 * lj;
                #pragma unroll
                for (int off = 32; off > 0; off >>= 1) {
                    const float ov = __shfl_down(lv, off);
                    const int   og = __shfl_down(gcol, off);
                    if (ov > lv) { lv = ov; gcol = og; }
                }
                lv = __shfl(lv, 0); gcol = __shfl(gcol, 0);
                if (it == 0) m = lv;
                if ((gcol & 63) == lane) used |= 1u << (gcol >> 6);
                const float e = expf(lv - m);
                denom += e;
                if (lane == 0) { pw[row][it] = e; pidx[row][it] = gcol; }
            }
            if (lane == 0) dinv[row] = 1.f / denom;
        } else {
            float lv = v[0];
            #pragma unroll
            for (int j = 1; j < 8; ++j) lv = fmaxf(lv, v[j]);
            #pragma unroll
            for (int off = 32; off > 0; off >>= 1) lv = fmaxf(lv, __shfl_down(lv, off));
            if (lane == 0) mrow[row] = lv;
        }
    }
    __syncthreads();

    const int row = t >> 4, c16 = t & 15;

    if (MODE != 0) {
        // ---- exp in place + denom ----
        const float m = mrow[row];
        float part = 0.f;
        for (int j = 0; j < 32; ++j) {
            const int col = c16 + 16 * j;
            if (col < kpad) {
                const float w = expf(S[row * 516 + col] - m);
                S[row * 516 + col] = w;
                part += w;
            }
        }
        part += __shfl_xor(part, 1);
        part += __shfl_xor(part, 2);
        part += __shfl_xor(part, 4);
        part += __shfl_xor(part, 8);
        if (c16 == 0) dinv[row] = 1.f / part;
        __syncthreads();
    }

    // ---- phase 3: PV + store (4 output dims per thread) ----
    const float inv = dinv[row];
    float a0 = 0.f, a1 = 0.f, a2 = 0.f, a3 = 0.f;
    if (MODE == 0) {
        #pragma unroll
        for (int j = 0; j < 16; ++j) {
            const float w = pw[row][j];
            const int kk = pidx[row][j];
            const ushort4 u = *(const ushort4*)(Vbase + (size_t)kk * DM + c16 * 4);
            a0 += w * u2f(u.x); a1 += w * u2f(u.y);
            a2 += w * u2f(u.z); a3 += w * u2f(u.w);
        }
    } else {
        const int kend = (MODE == 1) ? (q0 + row + 1 < kmax ? q0 + row + 1 : kmax) : kmax;
        for (int k = 0; k < kend; ++k) {
            const float w = S[row * 516 + k];   // broadcast within 16-lane group
            const ushort4 u = *(const ushort4*)(Vbase + (size_t)k * DM + c16 * 4);
            a0 += w * u2f(u.x); a1 += w * u2f(u.y);
            a2 += w * u2f(u.z); a3 += w * u2f(u.w);
        }
    }
    ushort4 o;
    { bf16 h0 = __float2bfloat16(a0 * inv); o.x = *(unsigned short*)&h0; }
    { bf16 h1 = __float2bfloat16(a1 * inv); o.y = *(unsigned short*)&h1; }
    { bf16 h2 = __float2bfloat16(a2 * inv); o.z = *(unsigned short*)&h2; }
    { bf16 h3 = __float2bfloat16(a3 * inv); o.w = *(unsigned short*)&h3; }
    *(ushort4*)(Qbase + (size_t)row * DM + c16 * 4) = o;
}

// ---------------- layernorm over D=512, optional residual; in-place safe ----------------
__global__ __launch_bounds__(256) void ln_off_k(
    const bf16* __restrict__ X, const bf16* __restrict__ R,
    const void* __restrict__ gb, unsigned goff,
    bf16* __restrict__ Out, const int* __restrict__ flagp)
{
    __shared__ float red[4];
    const int f = *flagp;
    const int t = threadIdx.x;
    const size_t base = (size_t)blockIdx.x * DM;
    float v0 = b2f(X[base + t]), v1 = b2f(X[base + t + 256]);
    if (R) { v0 += b2f(R[base + t]); v1 += b2f(R[base + t + 256]); }
    const float mean = block_sum256(v0 + v1, red) * (1.f / 512.f);
    const float d0 = v0 - mean, d1 = v1 - mean;
    const float var = block_sum256(d0 * d0 + d1 * d1, red) * (1.f / 512.f);
    const float rstd = rsqrtf(var + 1e-5f);
    Out[base + t]       = __float2bfloat16(d0 * rstd * ldw(gb, goff + t, f)       + ldw(gb, goff + 512 + t, f));
    Out[base + t + 256] = __float2bfloat16(d1 * rstd * ldw(gb, goff + t + 256, f) + ldw(gb, goff + 768 + t, f));
}

// ---------------- conv distill helpers ----------------
__global__ __launch_bounds__(256) void convw_k(const void* __restrict__ w, unsigned woff,
                                               bf16* __restrict__ wt, int total,
                                               const int* __restrict__ flagp) {
    const int f = *flagp;
    int i = blockIdx.x * 256 + threadIdx.x;
    if (i >= total) return;
    const int o = i / 1536, rem = i % 1536;
    const int j = rem >> 9, c = rem & 511;
    wt[i] = __float2bfloat16(ldw(w, woff + (unsigned)(o * 512 + c) * 3 + j, f));
}

__global__ __launch_bounds__(256) void convidx_k(int* __restrict__ idx, int Lc, int L, int total) {
    int i = blockIdx.x * 256 + threadIdx.x;
    if (i >= total) return;
    const int j = i / (16 * Lc), mrem = i % (16 * Lc);
    const int b = mrem / Lc, l = mrem % Lc;
    int src = l + j - 2;
    src %= L; if (src < 0) src += L;
    idx[i] = b * L + src;
}

__global__ __launch_bounds__(256) void bnstat1_k(const bf16* __restrict__ Y, float* __restrict__ part, int M) {
    const int t = threadIdx.x;
    float s0 = 0.f, q0 = 0.f, s1 = 0.f, q1 = 0.f;
    for (int r = blockIdx.x; r < M; r += gridDim.x) {
        const ushort2 u = *reinterpret_cast<const ushort2*>(Y + (size_t)r * DM + t * 2);
        const float a = u2f(u.x), c = u2f(u.y);
        s0 += a; q0 += a * a;
        s1 += c; q1 += c * c;
    }
    float* p = part + (size_t)blockIdx.x * 1024;
    p[2 * t] = s0; p[2 * t + 1] = s1;
    p[512 + 2 * t] = q0; p[512 + 2 * t + 1] = q1;
}

__global__ __launch_bounds__(256) void bnstat2_k(const float* __restrict__ part, float* __restrict__ stats,
                                                 int nchunk, int M) {
    const int ch = blockIdx.x * 256 + threadIdx.x;
    if (ch >= 512) return;
    float S = 0.f, Qs = 0.f;
    for (int c = 0; c < nchunk; ++c) { S += part[c * 1024 + ch]; Qs += part[c * 1024 + 512 + ch]; }
    const float mean = S / (float)M;
    const float var = Qs / (float)M - mean * mean;
    stats[ch] = mean;
    stats[512 + ch] = fmaxf(var, 0.f);
}

__global__ __launch_bounds__(256) void bnpool_k(
    const bf16* __restrict__ Yc, const float* __restrict__ stats,
    const void* __restrict__ g, const void* __restrict__ bb, unsigned off,
    bf16* __restrict__ Out, int Lc, int Lout, int total, const int* __restrict__ flagp)
{
    const int f = *flagp;
    int i = blockIdx.x * 256 + threadIdx.x;
    if (i >= total) return;
    const int ch = i & 511;
    const int lp = (i >> 9) % Lout;
    const int b = i / (512 * Lout);
    const float mean = stats[ch], var = stats[512 + ch];
    const float sc = ldw(g, off + ch, f) * rsqrtf(var + 1e-5f);
    const float sh = ldw(bb, off + ch, f) - mean * sc;
    float mx = -INFINITY;
    const int l0 = 2 * lp - 1;
    #pragma unroll
    for (int d = 0; d < 3; ++d) {
        const int l = l0 + d;
        if (l >= 0 && l < Lc) {
            float v = b2f(Yc[((size_t)b * Lc + l) * DM + ch]) * sc + sh;
            v = v > 0.f ? v : expm1f(v);  // ELU
            mx = fmaxf(mx, v);
        }
    }
    Out[((size_t)b * Lout + lp) * DM + ch] = __float2bfloat16(mx);
}

// ---------------- final projection to CO=7, dtype-matched store ----------------
__global__ __launch_bounds__(256) void fc_k(
    const bf16* __restrict__ Yn, const void* __restrict__ fcw, const void* __restrict__ fcb,
    void* __restrict__ out, int total, const int* __restrict__ flagp)
{
    const int f = *flagp;
    int i = blockIdx.x * 256 + threadIdx.x;
    if (i >= total) return;
    const int r = i / 7, co = i % 7;
    const bf16* yr = Yn + (size_t)r * DM;
    float acc = ldw(fcb, co, f);
    for (int d = 0; d < DM; ++d) acc += b2f(yr[d]) * ldw(fcw, d * 7 + co, f);
    if (f) ((bf16*)out)[i] = __float2bfloat16(acc);
    else   ((float*)out)[i] = acc;
}

// =============================================================================
extern "C" void kernel_launch(void* const* d_in, const int* in_sizes, int n_in,
                              void* d_out, int out_size, void* d_ws, size_t ws_size,
                              hipStream_t stream)
{
    const void* x_enc      = d_in[0];
    const void* x_mark_enc = d_in[1];
    const void* x_dec      = d_in[2];
    const void* x_mark_dec = d_in[3];
    const void* enc_vw = d_in[4];
    const void* enc_vb = d_in[5];
    const void* enc_mw = d_in[6];
    const void* enc_mb = d_in[7];
    const void* dec_vw = d_in[8];
    const void* dec_vb = d_in[9];
    const void* dec_mw = d_in[10];
    const void* dec_mb = d_in[11];
    const void* eW    = d_in[12];
    const void* ebi   = d_in[13];
    const void* effw1 = d_in[14];
    const void* effb1 = d_in[15];
    const void* effw2 = d_in[16];
    const void* effb2 = d_in[17];
    const void* eln1  = d_in[18];
    const void* eln2  = d_in[19];
    const void* cw    = d_in[20];
    const void* cb    = d_in[21];
    const void* cbn_g = d_in[22];
    const void* cbn_b = d_in[23];
    const void* enc_norm = d_in[24];
    const void* dsW   = d_in[25];
    const void* dsb   = d_in[26];
    const void* dcW   = d_in[27];
    const void* dcb   = d_in[28];
    const void* dffw1 = d_in[29];
    const void* dffb1 = d_in[30];
    const void* dffw2 = d_in[31];
    const void* dffb2 = d_in[32];
    const void* dln   = d_in[33];
    const void* dec_norm = d_in[34];
    const void* fcw   = d_in[35];
    const void* fcb   = d_in[36];

    // ---- workspace layout (~36.5 MiB + 4 B) ----
    char* wsp = (char*)d_ws;
    bf16* X  = (bf16*)wsp;
    bf16* Qb = (bf16*)(wsp + ((size_t)8 << 20));
    bf16* Kb = (bf16*)(wsp + ((size_t)16 << 20));
    bf16* VT = (bf16*)(wsp + ((size_t)24 << 20));
    bf16*  WTCb = Qb;                                             // conv Wt [512][1536], 1.5 MiB
    int*   IDX  = (int*)(wsp + ((size_t)8 << 20) + 1572864);
    float* PART = (float*)(wsp + ((size_t)8 << 20) + 1835008);
    float* STATS= (float*)(wsp + ((size_t)8 << 20) + 2097152);
    bf16* WT   = (bf16*)(wsp + ((size_t)32 << 20) + ((size_t)1 << 19));   // 4 MiB arena
    int*  FLAG = (int*)(wsp + ((size_t)36 << 20) + ((size_t)1 << 19));
    bf16* MEMb = X;
    bf16* Yd   = (bf16*)(wsp + (size_t)16 * 130 * 512 * 2);

    bf16* TS[4] = { WT, WT + 262144, WT + 524288, WT + 786432 };
    bf16* W1T = WT;
    bf16* W2T = WT + 1048576;

    auto cdiv = [](int a, int b) { return (a + b - 1) / b; };
    auto transp = [&](const void* W, unsigned off, bf16* out, int K, int N) {
        transp_k<<<dim3(N / 32, K / 32), 256, 0, stream>>>(W, off, out, K, N, FLAG);
    };
    auto mgemm = [&](const bf16* A, const bf16* Wt, const void* bias, unsigned boff,
                     bf16* C, int M, int N, int K, bool relu) {
        dim3 g(N / 128, cdiv(M, 128));
        if (relu) mgemm_k<false, true><<<g, 256, 0, stream>>>(
            (const short*)A, nullptr, (const short*)Wt, bias, boff, C, M, N, K, FLAG);
        else      mgemm_k<false, false><<<g, 256, 0, stream>>>(
            (const short*)A, nullptr, (const short*)Wt, bias, boff, C, M, N, K, FLAG);
    };

    // dtype sniff on x_mark_enc (32768 elems -> 16384 words safe for both dtypes)
    sniff_k<<<1, 256, 0, stream>>>((const unsigned*)x_mark_enc, 16384, FLAG);

    // ---- encoder embedding ----
    embed_k<<<cdiv(16 * 512 * 512, 256), 256, 0, stream>>>(
        x_enc, enc_vw, enc_vb, x_mark_enc, enc_mw, enc_mb, X, 16 * 512, 7, 4, FLAG);

    // ---- encoder ----
    int L = 512;
    for (int i = 0; i < 3; ++i) {
        const int rows = 16 * L;
        const unsigned W0 = (unsigned)i * 4u * 262144u;
        const unsigned b0 = (unsigned)i * 4u * 512u;
        for (int q = 0; q < 4; ++q) transp(eW, W0 + q * 262144u, TS[q], 512, 512);
        mgemm(X, TS[0], ebi, b0 + 0u * 512u, Qb, rows, 512, 512, false);
        mgemm(X, TS[1], ebi, b0 + 1u * 512u, Kb, rows, 512, 512, false);
        mgemm(X, TS[2], ebi, b0 + 2u * 512u, VT, rows, 512, 512, false);
        fattn_k<0><<<dim3(L / 16, 8, 16), 256, 0, stream>>>(Qb, Kb, VT, L, L);
        mgemm(Qb, TS[3], ebi, b0 + 3u * 512u, Kb, rows, 512, 512, false);
        ln_off_k<<<rows, 256, 0, stream>>>(X, Kb, eln1, (unsigned)i * 1024u, X, FLAG);

        transp(effw1, (unsigned)i * 1048576u, W1T, 512, 2048);
        transp(effw2, (unsigned)i * 1048576u, W2T, 2048, 512);
        for (int c0 = 0; c0 < rows; c0 += 2048) {
            const int mc = (rows - c0) < 2048 ? (rows - c0) : 2048;
            mgemm(X + (size_t)c0 * 512, W1T, effb1, (unsigned)i * 2048u, VT, mc, 2048, 512, true);
            mgemm(VT, W2T, effb2, (unsigned)i * 512u, Kb + (size_t)c0 * 512, mc, 512, 2048, false);
        }
        ln_off_k<<<rows, 256, 0, stream>>>(X, Kb, eln2, (unsigned)i * 1024u, X, FLAG);

        if (i < 2) {
            convw_k<<<cdiv(786432, 256), 256, 0, stream>>>(cw, (unsigned)i * 786432u, WTCb, 786432, FLAG);
            const int Lc = L + 2, Mc = 16 * Lc;
            convidx_k<<<cdiv(3 * Mc, 256), 256, 0, stream>>>(IDX, Lc, L, 3 * Mc);
            mgemm_k<true, false><<<dim3(4, cdiv(Mc, 128)), 256, 0, stream>>>(
                (const short*)X, IDX, (const short*)WTCb, cb, (unsigned)i * 512u,
                VT, Mc, 512, 1536, FLAG);
            bnstat1_k<<<32, 256, 0, stream>>>(VT, PART, Mc);
            bnstat2_k<<<2, 256, 0, stream>>>(PART, STATS, 32, Mc);
            const int Lout = (L + 1) / 2 + 1;   // 514->257, 259->130
            const int tot = 16 * Lout * 512;
            bnpool_k<<<cdiv(tot, 256), 256, 0, stream>>>(
                VT, STATS, cbn_g, cbn_b, (unsigned)i * 512u, X, Lc, Lout, tot, FLAG);
            L = Lout;
        }
    }
    const int Lm = L;  // 130
    ln_off_k<<<16 * Lm, 256, 0, stream>>>(X, nullptr, enc_norm, 0u, MEMb, FLAG);

    // ---- decoder embedding ----
    const int rowsD = 16 * 256;
    embed_k<<<cdiv(rowsD * 512, 256), 256, 0, stream>>>(
        x_dec, dec_vw, dec_vb, x_mark_dec, dec_mw, dec_mb, Yd, rowsD, 7, 4, FLAG);

    // ---- decoder ----
    for (int i = 0; i < 2; ++i) {
        const unsigned W0 = (unsigned)i * 4u * 262144u;
        const unsigned b0 = (unsigned)i * 4u * 512u;
        for (int q = 0; q < 4; ++q) transp(dsW, W0 + q * 262144u, TS[q], 512, 512);
        mgemm(Yd, TS[0], dsb, b0 + 0u * 512u, Qb, rowsD, 512, 512, false);
        mgemm(Yd, TS[1], dsb, b0 + 1u * 512u, Kb, rowsD, 512, 512, false);
        mgemm(Yd, TS[2], dsb, b0 + 2u * 512u, VT, rowsD, 512, 512, false);
        fattn_k<1><<<dim3(16, 8, 16), 256, 0, stream>>>(Qb, Kb, VT, 256, 256);
        mgemm(Qb, TS[3], dsb, b0 + 3u * 512u, Kb, rowsD, 512, 512, false);
        ln_off_k<<<rowsD, 256, 0, stream>>>(Yd, Kb, dln, (unsigned)(i * 3 + 0) * 1024u, Yd, FLAG);

        for (int q = 0; q < 4; ++q) transp(dcW, W0 + q * 262144u, TS[q], 512, 512);
        mgemm(Yd,   TS[0], dcb, b0 + 0u * 512u, Qb, rowsD, 512, 512, false);
        mgemm(MEMb, TS[1], dcb, b0 + 1u * 512u, Kb, 16 * Lm, 512, 512, false);
        mgemm(MEMb, TS[2], dcb, b0 + 2u * 512u, VT, 16 * Lm, 512, 512, false);
        fattn_k<2><<<dim3(16, 8, 16), 256, 0, stream>>>(Qb, Kb, VT, 256, Lm);
        mgemm(Qb, TS[3], dcb, b0 + 3u * 512u, Kb, rowsD, 512, 512, false);
        ln_off_k<<<rowsD, 256, 0, stream>>>(Yd, Kb, dln, (unsigned)(i * 3 + 1) * 1024u, Yd, FLAG);

        transp(dffw1, (unsigned)i * 1048576u, W1T, 512, 2048);
        transp(dffw2, (unsigned)i * 1048576u, W2T, 2048, 512);
        for (int c0 = 0; c0 < rowsD; c0 += 2048) {
            mgemm(Yd + (size_t)c0 * 512, W1T, dffb1, (unsigned)i * 2048u, VT, 2048, 2048, 512, true);
            mgemm(VT, W2T, dffb2, (unsigned)i * 512u, Kb + (size_t)c0 * 512, 2048, 512, 2048, false);
        }
        ln_off_k<<<rowsD, 256, 0, stream>>>(Yd, Kb, dln, (unsigned)(i * 3 + 2) * 1024u, Yd, FLAG);
    }

    ln_off_k<<<rowsD, 256, 0, stream>>>(Yd, nullptr, dec_norm, 0u, Qb, FLAG);
    fc_k<<<cdiv(rowsD * 7, 256), 256, 0, stream>>>(Qb, fcw, fcb, d_out, rowsD * 7, FLAG);
}

// Round 6
// 2614.585 us; speedup vs baseline: 4.8880x; 1.0508x over previous
//
#include <hip/hip_runtime.h>
#include <hip/hip_bf16.h>

// Informer forward, MI355X. Round 6: fattn phase-2 rework — packed-key (value|col)
// wave argmax via 6x shfl_xor umax, 4-row interleaving to hide DS latency; encoder
// attention grid coverage fixed (cdiv, clamped loads, masked stores).
// MFMA GEMMs, dtype sniffer, bf16 pipeline retained (round 5 passed, absmax 0.0122,
// 2747 us; encoder fattn was latency-bound on dependent shuffle chains).
// B=16, LE=512, LD=256, D=512, H=8, dk=64, DFF=2048, NE=3, ND=2, TOPK=16.
// Encoder lengths: 512 -> conv(514)/pool -> 257 -> conv(259)/pool -> 130.

#define DM 512
#define DK 64

using bf16 = __hip_bfloat16;
typedef short s8v __attribute__((ext_vector_type(8)));
typedef float f4v __attribute__((ext_vector_type(4)));

__device__ inline float b2f(bf16 x) { return __bfloat162float(x); }
__device__ inline float u2f(unsigned short u) { return __uint_as_float((unsigned)u << 16); }

// flag f: 1 = raw inputs are bf16, 0 = raw inputs are fp32. idx in ELEMENTS.
__device__ inline float ldw(const void* p, unsigned i, int f) {
    return f ? b2f(((const bf16*)p)[i]) : ((const float*)p)[i];
}

// order-preserving float->u32 (monotonic): flip all bits if negative, else flip sign
__device__ inline unsigned f2ord(float s) {
    unsigned u = __float_as_uint(s);
    return u ^ ((unsigned)((int)u >> 31) | 0x80000000u);
}

// ---------------- dtype sniffer ----------------
__global__ __launch_bounds__(256) void sniff_k(const unsigned* __restrict__ x, int nwords,
                                               int* __restrict__ flag) {
    __shared__ int red[4];
    const int t = threadIdx.x;
    int c = 0;
    for (int i = t; i < nwords; i += 256) c += ((x[i] & 0x7F80u) == 0x3F80u) ? 1 : 0;
    #pragma unroll
    for (int o = 32; o > 0; o >>= 1) c += __shfl_down(c, o);
    __syncthreads();
    if ((t & 63) == 0) red[t >> 6] = c;
    __syncthreads();
    if (t == 0) flag[0] = (red[0] + red[1] + red[2] + red[3] > nwords / 20) ? 1 : 0;
}

// ---------------- reductions (blockDim == 256) ----------------
__device__ inline float block_sum256(float v, float* red) {
    #pragma unroll
    for (int o = 32; o > 0; o >>= 1) v += __shfl_down(v, o);
    __syncthreads();
    if ((threadIdx.x & 63) == 0) red[threadIdx.x >> 6] = v;
    __syncthreads();
    return red[0] + red[1] + red[2] + red[3];
}

// ---------------- embedding ----------------
__global__ __launch_bounds__(256) void embed_k(
    const void* __restrict__ xv, const void* __restrict__ vw, const void* __restrict__ vb,
    const void* __restrict__ xm, const void* __restrict__ mw, const void* __restrict__ mb,
    bf16* __restrict__ Out, int rows, int Cv, int Cm, const int* __restrict__ flagp)
{
    const int f = *flagp;
    int i = blockIdx.x * 256 + threadIdx.x;
    if (i >= rows * DM) return;
    const int r = i >> 9, d = i & 511;
    float acc = ldw(vb, d, f) + ldw(mb, d, f);
    for (int c = 0; c < Cv; ++c) acc += ldw(xv, r * Cv + c, f) * ldw(vw, c * DM + d, f);
    for (int c = 0; c < Cm; ++c) acc += ldw(xm, r * Cm + c, f) * ldw(mw, c * DM + d, f);
    Out[i] = __float2bfloat16(acc);
}

// ---------------- weight transpose: raw [K][N] (flag dtype) -> bf16 [N][K] ----------------
__global__ __launch_bounds__(256) void transp_k(
    const void* __restrict__ W, unsigned off, bf16* __restrict__ out,
    int K, int N, const int* __restrict__ flagp)
{
    __shared__ float tile[32][33];
    const int f = *flagp;
    const int t = threadIdx.x;
    const int tx = t & 31, ty = t >> 5;               // 32 x 8
    const int n0 = blockIdx.x * 32, k0 = blockIdx.y * 32;
    #pragma unroll
    for (int i = 0; i < 4; ++i)
        tile[ty + 8 * i][tx] = ldw(W, off + (unsigned)(k0 + ty + 8 * i) * N + n0 + tx, f);
    __syncthreads();
    #pragma unroll
    for (int i = 0; i < 4; ++i)
        out[(size_t)(n0 + ty + 8 * i) * K + k0 + tx] = __float2bfloat16(tile[tx][ty + 8 * i]);
}

// ---------------- MFMA GEMM: C[M,N] = A[M,K] @ Wt[N,K]^T + bias, opt ReLU ----------------
template<bool G3, bool RELU>
__global__ __launch_bounds__(256) void mgemm_k(
    const short* __restrict__ A, const int* __restrict__ ridx,
    const short* __restrict__ Wt,
    const void* __restrict__ bias, unsigned boff0,
    bf16* __restrict__ C, int M, int N, int K, const int* __restrict__ flagp)
{
    __shared__ short As[128 * 40];   // pitch 40 shorts (80 B): 16B-aligned frag reads
    __shared__ short Ws[128 * 40];
    const int t = threadIdx.x;
    const int bm = blockIdx.y * 128, bn = blockIdx.x * 128;
    const int lane = t & 63, wave = t >> 6;
    const int mbase = (wave >> 1) * 64, nbase = (wave & 1) * 64;
    const int l15 = lane & 15, quad = lane >> 4;

    const int sm0 = t >> 2;              // staging row 0 (0..63)
    const int skq = (t & 3) * 8;         // staging k-chunk offset {0,8,16,24}

    f4v acc[4][4] = {};

    for (int k0 = 0; k0 < K; k0 += 32) {
        __syncthreads();
        #pragma unroll
        for (int h = 0; h < 2; ++h) {
            const int m = sm0 + h * 64;
            const int row = bm + m;
            size_t off;
            if (G3) {
                const int seg = k0 >> 9;
                const int r = (row < M) ? ridx[seg * M + row] : 0;
                off = (size_t)r * 512 + (k0 & 511) + skq;
            } else {
                const int rowc = row < M ? row : (M - 1);
                off = (size_t)rowc * K + k0 + skq;
            }
            *(s8v*)&As[m * 40 + skq] = *(const s8v*)(A + off);
        }
        #pragma unroll
        for (int h = 0; h < 2; ++h) {
            const int n = sm0 + h * 64;
            *(s8v*)&Ws[n * 40 + skq] = *(const s8v*)(Wt + (size_t)(bn + n) * K + k0 + skq);
        }
        __syncthreads();
        s8v af[4], bfv[4];
        #pragma unroll
        for (int i = 0; i < 4; ++i) {
            af[i]  = *(const s8v*)&As[(mbase + i * 16 + l15) * 40 + quad * 8];
            bfv[i] = *(const s8v*)&Ws[(nbase + i * 16 + l15) * 40 + quad * 8];
        }
        #pragma unroll
        for (int mi = 0; mi < 4; ++mi)
            #pragma unroll
            for (int ni = 0; ni < 4; ++ni)
                acc[mi][ni] = __builtin_amdgcn_mfma_f32_16x16x32_bf16(
                    af[mi], bfv[ni], acc[mi][ni], 0, 0, 0);
    }

    const int f = *flagp;
    float bv[4];
    #pragma unroll
    for (int ni = 0; ni < 4; ++ni)
        bv[ni] = ldw(bias, boff0 + (unsigned)(bn + nbase + ni * 16 + l15), f);

    #pragma unroll
    for (int mi = 0; mi < 4; ++mi) {
        #pragma unroll
        for (int r = 0; r < 4; ++r) {
            const int row = bm + mbase + mi * 16 + quad * 4 + r;
            if (row < M) {
                #pragma unroll
                for (int ni = 0; ni < 4; ++ni) {
                    float o = acc[mi][ni][r] + bv[ni];
                    if (RELU) o = fmaxf(o, 0.f);
                    C[(size_t)row * N + bn + nbase + ni * 16 + l15] = __float2bfloat16(o);
                }
            }
        }
    }
}

// ---------------- fused tile attention ----------------
// MODE 0: ProbSparse top-16 (encoder). MODE 1: causal (decoder self). MODE 2: plain (cross).
// Block = 256 threads, one (b, h, 16-query tile). O overwrites Q in place.
template<int MODE>
__global__ __launch_bounds__(256) void fattn_k(
    bf16* __restrict__ Q, const bf16* __restrict__ Kv, const bf16* __restrict__ Vv,
    int Lq, int Lk)
{
    __shared__ short Qs[16 * 72];
    __shared__ short Ks[64 * 72];
    __shared__ float S[16 * 516];
    __shared__ float pw[16][16];
    __shared__ int   pidx[16][16];
    __shared__ float mrow[16];
    __shared__ float dinv[16];

    const int t = threadIdx.x;
    const int q0 = blockIdx.x * 16, h = blockIdx.y, b = blockIdx.z;
    const int lane = t & 63, wave = t >> 6;
    const int l15 = lane & 15, quad = lane >> 4;

    const int qv = (Lq - q0) < 16 ? (Lq - q0) : 16;   // valid query rows in this tile

    const bf16* Kbase = Kv + ((size_t)b * Lk) * DM + h * DK;
    const bf16* Vbase = Vv + ((size_t)b * Lk) * DM + h * DK;
    bf16* Qbase = Q + ((size_t)(b * Lq + q0)) * DM + h * DK;

    const int kmax = (MODE == 1) ? (q0 + 16 < Lk ? q0 + 16 : Lk) : Lk;
    const int ntile = (kmax + 63) >> 6;
    const int kpad = ntile << 6;

    // stage Q tile (16 x 64), rows clamped to valid range
    if (t < 128) {
        const int qr = t >> 3;
        const int qsrc = qr < qv ? qr : qv - 1;
        *(s8v*)&Qs[qr * 72 + (t & 7) * 8] =
            *(const s8v*)(Qbase + (size_t)qsrc * DM + (t & 7) * 8);
    }

    // ---- phase 1: S = QK^T / 8 (+ masks), via MFMA ----
    for (int kt = 0; kt < ntile; ++kt) {
        __syncthreads();   // Qs ready (first iter) / Ks consumers done (later iters)
        const int k0 = kt << 6;
        int srow = k0 + (t >> 2); if (srow >= Lk) srow = Lk - 1;
        const bf16* kp = Kbase + (size_t)srow * DM + (t & 3) * 16;
        *(s8v*)&Ks[(t >> 2) * 72 + (t & 3) * 16]     = *(const s8v*)kp;
        *(s8v*)&Ks[(t >> 2) * 72 + (t & 3) * 16 + 8] = *(const s8v*)(kp + 8);
        __syncthreads();
        const s8v a0 = *(const s8v*)&Qs[l15 * 72 + quad * 8];
        const s8v a1 = *(const s8v*)&Qs[l15 * 72 + 32 + quad * 8];
        const s8v b0 = *(const s8v*)&Ks[(wave * 16 + l15) * 72 + quad * 8];
        const s8v b1 = *(const s8v*)&Ks[(wave * 16 + l15) * 72 + 32 + quad * 8];
        f4v acc = {0.f, 0.f, 0.f, 0.f};
        acc = __builtin_amdgcn_mfma_f32_16x16x32_bf16(a0, b0, acc, 0, 0, 0);
        acc = __builtin_amdgcn_mfma_f32_16x16x32_bf16(a1, b1, acc, 0, 0, 0);
        const int colg = k0 + wave * 16 + l15;
        #pragma unroll
        for (int r = 0; r < 4; ++r) {
            const int qrow = quad * 4 + r;
            float s = acc[r] * 0.125f;
            if (colg >= Lk) s = -1e9f;
            if (MODE == 1 && colg > q0 + qrow) s = -1e9f;
            S[qrow * 516 + colg] = s;
        }
    }
    __syncthreads();

    // ---- phase 2 ----
    if (MODE == 0) {
        // per-row top-16 via packed keys (ord(value)|col), 4 rows interleaved for ILP
        unsigned key[4][8];
        float mr[4], den[4];
        #pragma unroll
        for (int r = 0; r < 4; ++r) {
            const int row = wave * 4 + r;
            #pragma unroll
            for (int j = 0; j < 8; ++j) {
                const int col = lane + 64 * j;
                key[r][j] = (col < kpad)
                    ? ((f2ord(S[row * 516 + col]) & 0xFFFFFE00u) | (unsigned)col)
                    : 0u;
            }
            den[r] = 0.f;
            mr[r] = 0.f;
        }
        for (int it = 0; it < 16; ++it) {
            #pragma unroll
            for (int r = 0; r < 4; ++r) {
                unsigned mx = key[r][0];
                #pragma unroll
                for (int j = 1; j < 8; ++j) mx = mx > key[r][j] ? mx : key[r][j];
                #pragma unroll
                for (int off = 1; off < 64; off <<= 1) {
                    const unsigned o = __shfl_xor(mx, off);
                    mx = mx > o ? mx : o;
                }
                #pragma unroll
                for (int j = 0; j < 8; ++j) if (key[r][j] == mx) key[r][j] = 0u;
                const int col = (int)(mx & 511u);
                const int row = wave * 4 + r;
                const float sval = S[row * 516 + col];   // broadcast read, exact value
                if (it == 0) mr[r] = sval;
                const float e = expf(sval - mr[r]);
                den[r] += e;
                if (lane == 0) { pw[row][it] = e; pidx[row][it] = col; }
            }
        }
        #pragma unroll
        for (int r = 0; r < 4; ++r)
            if (lane == 0) dinv[wave * 4 + r] = 1.f / den[r];
    } else {
        // row max, 4 rows interleaved, xor-butterfly
        float mx[4];
        #pragma unroll
        for (int r = 0; r < 4; ++r) {
            const int row = wave * 4 + r;
            float lv = -INFINITY;
            #pragma unroll
            for (int j = 0; j < 8; ++j) {
                const int col = lane + 64 * j;
                if (col < kpad) lv = fmaxf(lv, S[row * 516 + col]);
            }
            mx[r] = lv;
        }
        #pragma unroll
        for (int off = 1; off < 64; off <<= 1) {
            #pragma unroll
            for (int r = 0; r < 4; ++r) mx[r] = fmaxf(mx[r], __shfl_xor(mx[r], off));
        }
        #pragma unroll
        for (int r = 0; r < 4; ++r)
            if (lane == 0) mrow[wave * 4 + r] = mx[r];
    }
    __syncthreads();

    const int row = t >> 4, c16 = t & 15;

    if (MODE != 0) {
        // ---- exp in place + denom ----
        const float m = mrow[row];
        float part = 0.f;
        for (int j = 0; j < 32; ++j) {
            const int col = c16 + 16 * j;
            if (col < kpad) {
                const float w = expf(S[row * 516 + col] - m);
                S[row * 516 + col] = w;
                part += w;
            }
        }
        part += __shfl_xor(part, 1);
        part += __shfl_xor(part, 2);
        part += __shfl_xor(part, 4);
        part += __shfl_xor(part, 8);
        if (c16 == 0) dinv[row] = 1.f / part;
        __syncthreads();
    }

    // ---- phase 3: PV + store (4 output dims per thread) ----
    const float inv = dinv[row];
    float a0 = 0.f, a1 = 0.f, a2 = 0.f, a3 = 0.f;
    if (MODE == 0) {
        #pragma unroll
        for (int j = 0; j < 16; ++j) {
            const float w = pw[row][j];
            const int kk = pidx[row][j];
            const ushort4 u = *(const ushort4*)(Vbase + (size_t)kk * DM + c16 * 4);
            a0 += w * u2f(u.x); a1 += w * u2f(u.y);
            a2 += w * u2f(u.z); a3 += w * u2f(u.w);
        }
    } else {
        const int kend = (MODE == 1) ? (q0 + row + 1 < kmax ? q0 + row + 1 : kmax) : kmax;
        for (int k = 0; k < kend; ++k) {
            const float w = S[row * 516 + k];   // broadcast within 16-lane group
            const ushort4 u = *(const ushort4*)(Vbase + (size_t)k * DM + c16 * 4);
            a0 += w * u2f(u.x); a1 += w * u2f(u.y);
            a2 += w * u2f(u.z); a3 += w * u2f(u.w);
        }
    }
    if (row < qv) {
        ushort4 o;
        { bf16 h0 = __float2bfloat16(a0 * inv); o.x = *(unsigned short*)&h0; }
        { bf16 h1 = __float2bfloat16(a1 * inv); o.y = *(unsigned short*)&h1; }
        { bf16 h2 = __float2bfloat16(a2 * inv); o.z = *(unsigned short*)&h2; }
        { bf16 h3 = __float2bfloat16(a3 * inv); o.w = *(unsigned short*)&h3; }
        *(ushort4*)(Qbase + (size_t)row * DM + c16 * 4) = o;
    }
}

// ---------------- layernorm over D=512, optional residual; in-place safe ----------------
__global__ __launch_bounds__(256) void ln_off_k(
    const bf16* __restrict__ X, const bf16* __restrict__ R,
    const void* __restrict__ gb, unsigned goff,
    bf16* __restrict__ Out, const int* __restrict__ flagp)
{
    __shared__ float red[4];
    const int f = *flagp;
    const int t = threadIdx.x;
    const size_t base = (size_t)blockIdx.x * DM;
    float v0 = b2f(X[base + t]), v1 = b2f(X[base + t + 256]);
    if (R) { v0 += b2f(R[base + t]); v1 += b2f(R[base + t + 256]); }
    const float mean = block_sum256(v0 + v1, red) * (1.f / 512.f);
    const float d0 = v0 - mean, d1 = v1 - mean;
    const float var = block_sum256(d0 * d0 + d1 * d1, red) * (1.f / 512.f);
    const float rstd = rsqrtf(var + 1e-5f);
    Out[base + t]       = __float2bfloat16(d0 * rstd * ldw(gb, goff + t, f)       + ldw(gb, goff + 512 + t, f));
    Out[base + t + 256] = __float2bfloat16(d1 * rstd * ldw(gb, goff + t + 256, f) + ldw(gb, goff + 768 + t, f));
}

// ---------------- conv distill helpers ----------------
__global__ __launch_bounds__(256) void convw_k(const void* __restrict__ w, unsigned woff,
                                               bf16* __restrict__ wt, int total,
                                               const int* __restrict__ flagp) {
    const int f = *flagp;
    int i = blockIdx.x * 256 + threadIdx.x;
    if (i >= total) return;
    const int o = i / 1536, rem = i % 1536;
    const int j = rem >> 9, c = rem & 511;
    wt[i] = __float2bfloat16(ldw(w, woff + (unsigned)(o * 512 + c) * 3 + j, f));
}

__global__ __launch_bounds__(256) void convidx_k(int* __restrict__ idx, int Lc, int L, int total) {
    int i = blockIdx.x * 256 + threadIdx.x;
    if (i >= total) return;
    const int j = i / (16 * Lc), mrem = i % (16 * Lc);
    const int b = mrem / Lc, l = mrem % Lc;
    int src = l + j - 2;
    src %= L; if (src < 0) src += L;
    idx[i] = b * L + src;
}

__global__ __launch_bounds__(256) void bnstat1_k(const bf16* __restrict__ Y, float* __restrict__ part, int M) {
    const int t = threadIdx.x;
    float s0 = 0.f, q0 = 0.f, s1 = 0.f, q1 = 0.f;
    for (int r = blockIdx.x; r < M; r += gridDim.x) {
        const ushort2 u = *reinterpret_cast<const ushort2*>(Y + (size_t)r * DM + t * 2);
        const float a = u2f(u.x), c = u2f(u.y);
        s0 += a; q0 += a * a;
        s1 += c; q1 += c * c;
    }
    float* p = part + (size_t)blockIdx.x * 1024;
    p[2 * t] = s0; p[2 * t + 1] = s1;
    p[512 + 2 * t] = q0; p[512 + 2 * t + 1] = q1;
}

__global__ __launch_bounds__(256) void bnstat2_k(const float* __restrict__ part, float* __restrict__ stats,
                                                 int nchunk, int M) {
    const int ch = blockIdx.x * 256 + threadIdx.x;
    if (ch >= 512) return;
    float S = 0.f, Qs = 0.f;
    for (int c = 0; c < nchunk; ++c) { S += part[c * 1024 + ch]; Qs += part[c * 1024 + 512 + ch]; }
    const float mean = S / (float)M;
    const float var = Qs / (float)M - mean * mean;
    stats[ch] = mean;
    stats[512 + ch] = fmaxf(var, 0.f);
}

__global__ __launch_bounds__(256) void bnpool_k(
    const bf16* __restrict__ Yc, const float* __restrict__ stats,
    const void* __restrict__ g, const void* __restrict__ bb, unsigned off,
    bf16* __restrict__ Out, int Lc, int Lout, int total, const int* __restrict__ flagp)
{
    const int f = *flagp;
    int i = blockIdx.x * 256 + threadIdx.x;
    if (i >= total) return;
    const int ch = i & 511;
    const int lp = (i >> 9) % Lout;
    const int b = i / (512 * Lout);
    const float mean = stats[ch], var = stats[512 + ch];
    const float sc = ldw(g, off + ch, f) * rsqrtf(var + 1e-5f);
    const float sh = ldw(bb, off + ch, f) - mean * sc;
    float mx = -INFINITY;
    const int l0 = 2 * lp - 1;
    #pragma unroll
    for (int d = 0; d < 3; ++d) {
        const int l = l0 + d;
        if (l >= 0 && l < Lc) {
            float v = b2f(Yc[((size_t)b * Lc + l) * DM + ch]) * sc + sh;
            v = v > 0.f ? v : expm1f(v);  // ELU
            mx = fmaxf(mx, v);
        }
    }
    Out[((size_t)b * Lout + lp) * DM + ch] = __float2bfloat16(mx);
}

// ---------------- final projection to CO=7, dtype-matched store ----------------
__global__ __launch_bounds__(256) void fc_k(
    const bf16* __restrict__ Yn, const void* __restrict__ fcw, const void* __restrict__ fcb,
    void* __restrict__ out, int total, const int* __restrict__ flagp)
{
    const int f = *flagp;
    int i = blockIdx.x * 256 + threadIdx.x;
    if (i >= total) return;
    const int r = i / 7, co = i % 7;
    const bf16* yr = Yn + (size_t)r * DM;
    float acc = ldw(fcb, co, f);
    for (int d = 0; d < DM; ++d) acc += b2f(yr[d]) * ldw(fcw, d * 7 + co, f);
    if (f) ((bf16*)out)[i] = __float2bfloat16(acc);
    else   ((float*)out)[i] = acc;
}

// =============================================================================
extern "C" void kernel_launch(void* const* d_in, const int* in_sizes, int n_in,
                              void* d_out, int out_size, void* d_ws, size_t ws_size,
                              hipStream_t stream)
{
    const void* x_enc      = d_in[0];
    const void* x_mark_enc = d_in[1];
    const void* x_dec      = d_in[2];
    const void* x_mark_dec = d_in[3];
    const void* enc_vw = d_in[4];
    const void* enc_vb = d_in[5];
    const void* enc_mw = d_in[6];
    const void* enc_mb = d_in[7];
    const void* dec_vw = d_in[8];
    const void* dec_vb = d_in[9];
    const void* dec_mw = d_in[10];
    const void* dec_mb = d_in[11];
    const void* eW    = d_in[12];
    const void* ebi   = d_in[13];
    const void* effw1 = d_in[14];
    const void* effb1 = d_in[15];
    const void* effw2 = d_in[16];
    const void* effb2 = d_in[17];
    const void* eln1  = d_in[18];
    const void* eln2  = d_in[19];
    const void* cw    = d_in[20];
    const void* cb    = d_in[21];
    const void* cbn_g = d_in[22];
    const void* cbn_b = d_in[23];
    const void* enc_norm = d_in[24];
    const void* dsW   = d_in[25];
    const void* dsb   = d_in[26];
    const void* dcW   = d_in[27];
    const void* dcb   = d_in[28];
    const void* dffw1 = d_in[29];
    const void* dffb1 = d_in[30];
    const void* dffw2 = d_in[31];
    const void* dffb2 = d_in[32];
    const void* dln   = d_in[33];
    const void* dec_norm = d_in[34];
    const void* fcw   = d_in[35];
    const void* fcb   = d_in[36];

    // ---- workspace layout (~36.5 MiB + 4 B) ----
    char* wsp = (char*)d_ws;
    bf16* X  = (bf16*)wsp;
    bf16* Qb = (bf16*)(wsp + ((size_t)8 << 20));
    bf16* Kb = (bf16*)(wsp + ((size_t)16 << 20));
    bf16* VT = (bf16*)(wsp + ((size_t)24 << 20));
    bf16*  WTCb = Qb;                                             // conv Wt [512][1536], 1.5 MiB
    int*   IDX  = (int*)(wsp + ((size_t)8 << 20) + 1572864);
    float* PART = (float*)(wsp + ((size_t)8 << 20) + 1835008);
    float* STATS= (float*)(wsp + ((size_t)8 << 20) + 2097152);
    bf16* WT   = (bf16*)(wsp + ((size_t)32 << 20) + ((size_t)1 << 19));   // 4 MiB arena
    int*  FLAG = (int*)(wsp + ((size_t)36 << 20) + ((size_t)1 << 19));
    bf16* MEMb = X;
    bf16* Yd   = (bf16*)(wsp + (size_t)16 * 130 * 512 * 2);

    bf16* TS[4] = { WT, WT + 262144, WT + 524288, WT + 786432 };
    bf16* W1T = WT;
    bf16* W2T = WT + 1048576;

    auto cdiv = [](int a, int b) { return (a + b - 1) / b; };
    auto transp = [&](const void* W, unsigned off, bf16* out, int K, int N) {
        transp_k<<<dim3(N / 32, K / 32), 256, 0, stream>>>(W, off, out, K, N, FLAG);
    };
    auto mgemm = [&](const bf16* A, const bf16* Wt, const void* bias, unsigned boff,
                     bf16* C, int M, int N, int K, bool relu) {
        dim3 g(N / 128, cdiv(M, 128));
        if (relu) mgemm_k<false, true><<<g, 256, 0, stream>>>(
            (const short*)A, nullptr, (const short*)Wt, bias, boff, C, M, N, K, FLAG);
        else      mgemm_k<false, false><<<g, 256, 0, stream>>>(
            (const short*)A, nullptr, (const short*)Wt, bias, boff, C, M, N, K, FLAG);
    };

    // dtype sniff on x_mark_enc (32768 elems -> 16384 words safe for both dtypes)
    sniff_k<<<1, 256, 0, stream>>>((const unsigned*)x_mark_enc, 16384, FLAG);

    // ---- encoder embedding ----
    embed_k<<<cdiv(16 * 512 * 512, 256), 256, 0, stream>>>(
        x_enc, enc_vw, enc_vb, x_mark_enc, enc_mw, enc_mb, X, 16 * 512, 7, 4, FLAG);

    // ---- encoder ----
    int L = 512;
    for (int i = 0; i < 3; ++i) {
        const int rows = 16 * L;
        const unsigned W0 = (unsigned)i * 4u * 262144u;
        const unsigned b0 = (unsigned)i * 4u * 512u;
        for (int q = 0; q < 4; ++q) transp(eW, W0 + q * 262144u, TS[q], 512, 512);
        mgemm(X, TS[0], ebi, b0 + 0u * 512u, Qb, rows, 512, 512, false);
        mgemm(X, TS[1], ebi, b0 + 1u * 512u, Kb, rows, 512, 512, false);
        mgemm(X, TS[2], ebi, b0 + 2u * 512u, VT, rows, 512, 512, false);
        fattn_k<0><<<dim3(cdiv(L, 16), 8, 16), 256, 0, stream>>>(Qb, Kb, VT, L, L);
        mgemm(Qb, TS[3], ebi, b0 + 3u * 512u, Kb, rows, 512, 512, false);
        ln_off_k<<<rows, 256, 0, stream>>>(X, Kb, eln1, (unsigned)i * 1024u, X, FLAG);

        transp(effw1, (unsigned)i * 1048576u, W1T, 512, 2048);
        transp(effw2, (unsigned)i * 1048576u, W2T, 2048, 512);
        for (int c0 = 0; c0 < rows; c0 += 2048) {
            const int mc = (rows - c0) < 2048 ? (rows - c0) : 2048;
            mgemm(X + (size_t)c0 * 512, W1T, effb1, (unsigned)i * 2048u, VT, mc, 2048, 512, true);
            mgemm(VT, W2T, effb2, (unsigned)i * 512u, Kb + (size_t)c0 * 512, mc, 512, 2048, false);
        }
        ln_off_k<<<rows, 256, 0, stream>>>(X, Kb, eln2, (unsigned)i * 1024u, X, FLAG);

        if (i < 2) {
            convw_k<<<cdiv(786432, 256), 256, 0, stream>>>(cw, (unsigned)i * 786432u, WTCb, 786432, FLAG);
            const int Lc = L + 2, Mc = 16 * Lc;
            convidx_k<<<cdiv(3 * Mc, 256), 256, 0, stream>>>(IDX, Lc, L, 3 * Mc);
            mgemm_k<true, false><<<dim3(4, cdiv(Mc, 128)), 256, 0, stream>>>(
                (const short*)X, IDX, (const short*)WTCb, cb, (unsigned)i * 512u,
                VT, Mc, 512, 1536, FLAG);
            bnstat1_k<<<32, 256, 0, stream>>>(VT, PART, Mc);
            bnstat2_k<<<2, 256, 0, stream>>>(PART, STATS, 32, Mc);
            const int Lout = (L + 1) / 2 + 1;   // 514->257, 259->130
            const int tot = 16 * Lout * 512;
            bnpool_k<<<cdiv(tot, 256), 256, 0, stream>>>(
                VT, STATS, cbn_g, cbn_b, (unsigned)i * 512u, X, Lc, Lout, tot, FLAG);
            L = Lout;
        }
    }
    const int Lm = L;  // 130
    ln_off_k<<<16 * Lm, 256, 0, stream>>>(X, nullptr, enc_norm, 0u, MEMb, FLAG);

    // ---- decoder embedding ----
    const int rowsD = 16 * 256;
    embed_k<<<cdiv(rowsD * 512, 256), 256, 0, stream>>>(
        x_dec, dec_vw, dec_vb, x_mark_dec, dec_mw, dec_mb, Yd, rowsD, 7, 4, FLAG);

    // ---- decoder ----
    for (int i = 0; i < 2; ++i) {
        const unsigned W0 = (unsigned)i * 4u * 262144u;
        const unsigned b0 = (unsigned)i * 4u * 512u;
        for (int q = 0; q < 4; ++q) transp(dsW, W0 + q * 262144u, TS[q], 512, 512);
        mgemm(Yd, TS[0], dsb, b0 + 0u * 512u, Qb, rowsD, 512, 512, false);
        mgemm(Yd, TS[1], dsb, b0 + 1u * 512u, Kb, rowsD, 512, 512, false);
        mgemm(Yd, TS[2], dsb, b0 + 2u * 512u, VT, rowsD, 512, 512, false);
        fattn_k<1><<<dim3(16, 8, 16), 256, 0, stream>>>(Qb, Kb, VT, 256, 256);
        mgemm(Qb, TS[3], dsb, b0 + 3u * 512u, Kb, rowsD, 512, 512, false);
        ln_off_k<<<rowsD, 256, 0, stream>>>(Yd, Kb, dln, (unsigned)(i * 3 + 0) * 1024u, Yd, FLAG);

        for (int q = 0; q < 4; ++q) transp(dcW, W0 + q * 262144u, TS[q], 512, 512);
        mgemm(Yd,   TS[0], dcb, b0 + 0u * 512u, Qb, rowsD, 512, 512, false);
        mgemm(MEMb, TS[1], dcb, b0 + 1u * 512u, Kb, 16 * Lm, 512, 512, false);
        mgemm(MEMb, TS[2], dcb, b0 + 2u * 512u, VT, 16 * Lm, 512, 512, false);
        fattn_k<2><<<dim3(16, 8, 16), 256, 0, stream>>>(Qb, Kb, VT, 256, Lm);
        mgemm(Qb, TS[3], dcb, b0 + 3u * 512u, Kb, rowsD, 512, 512, false);
        ln_off_k<<<rowsD, 256, 0, stream>>>(Yd, Kb, dln, (unsigned)(i * 3 + 1) * 1024u, Yd, FLAG);

        transp(dffw1, (unsigned)i * 1048576u, W1T, 512, 2048);
        transp(dffw2, (unsigned)i * 1048576u, W2T, 2048, 512);
        for (int c0 = 0; c0 < rowsD; c0 += 2048) {
            mgemm(Yd + (size_t)c0 * 512, W1T, dffb1, (unsigned)i * 2048u, VT, 2048, 2048, 512, true);
            mgemm(VT, W2T, dffb2, (unsigned)i * 512u, Kb + (size_t)c0 * 512, 2048, 512, 2048, false);
        }
        ln_off_k<<<rowsD, 256, 0, stream>>>(Yd, Kb, dln, (unsigned)(i * 3 + 2) * 1024u, Yd, FLAG);
    }

    ln_off_k<<<rowsD, 256, 0, stream>>>(Yd, nullptr, dec_norm, 0u, Qb, FLAG);
    fc_k<<<cdiv(rowsD * 7, 256), 256, 0, stream>>>(Qb, fcw, fcb, d_out, rowsD * 7, FLAG);
}

// Round 7
// 2028.111 us; speedup vs baseline: 6.3015x; 1.2892x over previous
//
#include <hip/hip_runtime.h>
#include <hip/hip_bf16.h>

// Informer forward, MI355X. Round 7: GEMM occupancy + fusion round.
// - Fused QKV projection (N=1536) into strided QKV buffer; fattn reads q/k/v via strides.
// - mgemm64_k (128 thr, 128x64 tile) for all N=512 GEMMs -> 2x blocks/CU.
// - FFN unchunked via dedicated HID region (ws ~78 MB; 111 MB known-safe from round 1).
// - Batched weight transposes (blockIdx.z), fused cross-K/V GEMM (N=1024).
// Retained: dtype sniffer, MFMA GEMM cores, packed-key top-16 fattn (round 6 passed,
// absmax 0.0117, 2615 us; GEMM path ~100 TF at 1 block/CU was the bottleneck).
// B=16, LE=512, LD=256, D=512, H=8, dk=64, DFF=2048, NE=3, ND=2, TOPK=16.
// Encoder lengths: 512 -> conv(514)/pool -> 257 -> conv(259)/pool -> 130.

#define DM 512
#define DK 64

using bf16 = __hip_bfloat16;
typedef short s8v __attribute__((ext_vector_type(8)));
typedef float f4v __attribute__((ext_vector_type(4)));

__device__ inline float b2f(bf16 x) { return __bfloat162float(x); }
__device__ inline float u2f(unsigned short u) { return __uint_as_float((unsigned)u << 16); }

// flag f: 1 = raw inputs are bf16, 0 = raw inputs are fp32. idx in ELEMENTS.
__device__ inline float ldw(const void* p, unsigned i, int f) {
    return f ? b2f(((const bf16*)p)[i]) : ((const float*)p)[i];
}

// order-preserving float->u32 (monotonic)
__device__ inline unsigned f2ord(float s) {
    unsigned u = __float_as_uint(s);
    return u ^ ((unsigned)((int)u >> 31) | 0x80000000u);
}

// ---------------- dtype sniffer ----------------
__global__ __launch_bounds__(256) void sniff_k(const unsigned* __restrict__ x, int nwords,
                                               int* __restrict__ flag) {
    __shared__ int red[4];
    const int t = threadIdx.x;
    int c = 0;
    for (int i = t; i < nwords; i += 256) c += ((x[i] & 0x7F80u) == 0x3F80u) ? 1 : 0;
    #pragma unroll
    for (int o = 32; o > 0; o >>= 1) c += __shfl_down(c, o);
    __syncthreads();
    if ((t & 63) == 0) red[t >> 6] = c;
    __syncthreads();
    if (t == 0) flag[0] = (red[0] + red[1] + red[2] + red[3] > nwords / 20) ? 1 : 0;
}

// ---------------- reductions (blockDim == 256) ----------------
__device__ inline float block_sum256(float v, float* red) {
    #pragma unroll
    for (int o = 32; o > 0; o >>= 1) v += __shfl_down(v, o);
    __syncthreads();
    if ((threadIdx.x & 63) == 0) red[threadIdx.x >> 6] = v;
    __syncthreads();
    return red[0] + red[1] + red[2] + red[3];
}

// ---------------- embedding ----------------
__global__ __launch_bounds__(256) void embed_k(
    const void* __restrict__ xv, const void* __restrict__ vw, const void* __restrict__ vb,
    const void* __restrict__ xm, const void* __restrict__ mw, const void* __restrict__ mb,
    bf16* __restrict__ Out, int rows, int Cv, int Cm, const int* __restrict__ flagp)
{
    const int f = *flagp;
    int i = blockIdx.x * 256 + threadIdx.x;
    if (i >= rows * DM) return;
    const int r = i >> 9, d = i & 511;
    float acc = ldw(vb, d, f) + ldw(mb, d, f);
    for (int c = 0; c < Cv; ++c) acc += ldw(xv, r * Cv + c, f) * ldw(vw, c * DM + d, f);
    for (int c = 0; c < Cm; ++c) acc += ldw(xm, r * Cm + c, f) * ldw(mw, c * DM + d, f);
    Out[i] = __float2bfloat16(acc);
}

// ---------------- weight transpose: raw [K][N] -> bf16 [N][K]; z batches sub-mats ----------------
__global__ __launch_bounds__(256) void transp_k(
    const void* __restrict__ W, unsigned off, unsigned zstride, bf16* __restrict__ out,
    int K, int N, const int* __restrict__ flagp)
{
    __shared__ float tile[32][33];
    const int f = *flagp;
    const unsigned zo = blockIdx.z * zstride;
    const int t = threadIdx.x;
    const int tx = t & 31, ty = t >> 5;               // 32 x 8
    const int n0 = blockIdx.x * 32, k0 = blockIdx.y * 32;
    #pragma unroll
    for (int i = 0; i < 4; ++i)
        tile[ty + 8 * i][tx] = ldw(W, off + zo + (unsigned)(k0 + ty + 8 * i) * N + n0 + tx, f);
    __syncthreads();
    #pragma unroll
    for (int i = 0; i < 4; ++i)
        out[(size_t)zo + (size_t)(n0 + ty + 8 * i) * K + k0 + tx] = __float2bfloat16(tile[tx][ty + 8 * i]);
}

// ---------------- MFMA GEMM 128x128 (256 thr): C = A[M,K]@Wt[N,K]^T + bias ----------------
template<bool G3, bool RELU>
__global__ __launch_bounds__(256) void mgemm_k(
    const short* __restrict__ A, const int* __restrict__ ridx,
    const short* __restrict__ Wt,
    const void* __restrict__ bias, unsigned boff0,
    bf16* __restrict__ C, int M, int N, int K, int lda, int ldc,
    const int* __restrict__ flagp)
{
    __shared__ short As[128 * 40];
    __shared__ short Ws[128 * 40];
    const int t = threadIdx.x;
    const int bm = blockIdx.y * 128, bn = blockIdx.x * 128;
    const int lane = t & 63, wave = t >> 6;
    const int mbase = (wave >> 1) * 64, nbase = (wave & 1) * 64;
    const int l15 = lane & 15, quad = lane >> 4;

    const int sm0 = t >> 2;
    const int skq = (t & 3) * 8;

    f4v acc[4][4] = {};

    for (int k0 = 0; k0 < K; k0 += 32) {
        __syncthreads();
        #pragma unroll
        for (int h = 0; h < 2; ++h) {
            const int m = sm0 + h * 64;
            const int row = bm + m;
            size_t off;
            if (G3) {
                const int seg = k0 >> 9;
                const int r = (row < M) ? ridx[seg * M + row] : 0;
                off = (size_t)r * lda + (k0 & 511) + skq;
            } else {
                const int rowc = row < M ? row : (M - 1);
                off = (size_t)rowc * lda + k0 + skq;
            }
            *(s8v*)&As[m * 40 + skq] = *(const s8v*)(A + off);
        }
        #pragma unroll
        for (int h = 0; h < 2; ++h) {
            const int n = sm0 + h * 64;
            *(s8v*)&Ws[n * 40 + skq] = *(const s8v*)(Wt + (size_t)(bn + n) * K + k0 + skq);
        }
        __syncthreads();
        s8v af[4], bfv[4];
        #pragma unroll
        for (int i = 0; i < 4; ++i) {
            af[i]  = *(const s8v*)&As[(mbase + i * 16 + l15) * 40 + quad * 8];
            bfv[i] = *(const s8v*)&Ws[(nbase + i * 16 + l15) * 40 + quad * 8];
        }
        #pragma unroll
        for (int mi = 0; mi < 4; ++mi)
            #pragma unroll
            for (int ni = 0; ni < 4; ++ni)
                acc[mi][ni] = __builtin_amdgcn_mfma_f32_16x16x32_bf16(
                    af[mi], bfv[ni], acc[mi][ni], 0, 0, 0);
    }

    const int f = *flagp;
    float bv[4];
    #pragma unroll
    for (int ni = 0; ni < 4; ++ni)
        bv[ni] = ldw(bias, boff0 + (unsigned)(bn + nbase + ni * 16 + l15), f);

    #pragma unroll
    for (int mi = 0; mi < 4; ++mi) {
        #pragma unroll
        for (int r = 0; r < 4; ++r) {
            const int row = bm + mbase + mi * 16 + quad * 4 + r;
            if (row < M) {
                #pragma unroll
                for (int ni = 0; ni < 4; ++ni) {
                    float o = acc[mi][ni][r] + bv[ni];
                    if (RELU) o = fmaxf(o, 0.f);
                    C[(size_t)row * ldc + bn + nbase + ni * 16 + l15] = __float2bfloat16(o);
                }
            }
        }
    }
}

// ---------------- MFMA GEMM 128x64 (128 thr, 2 waves): for N=512-class GEMMs ----------------
template<bool G3, bool RELU>
__global__ __launch_bounds__(128) void mgemm64_k(
    const short* __restrict__ A, const int* __restrict__ ridx,
    const short* __restrict__ Wt,
    const void* __restrict__ bias, unsigned boff0,
    bf16* __restrict__ C, int M, int N, int K, int lda, int ldc,
    const int* __restrict__ flagp)
{
    __shared__ short As[128 * 40];
    __shared__ short Ws[64 * 40];
    const int t = threadIdx.x;
    const int bm = blockIdx.y * 128, bn = blockIdx.x * 64;
    const int lane = t & 63, wave = t >> 6;
    const int mbase = wave * 64;
    const int l15 = lane & 15, quad = lane >> 4;

    const int sr = t >> 2;               // 0..31
    const int skq = (t & 3) * 8;

    f4v acc[4][4] = {};

    for (int k0 = 0; k0 < K; k0 += 32) {
        __syncthreads();
        #pragma unroll
        for (int h = 0; h < 4; ++h) {
            const int m = sr + h * 32;
            const int row = bm + m;
            size_t off;
            if (G3) {
                const int seg = k0 >> 9;
                const int r = (row < M) ? ridx[seg * M + row] : 0;
                off = (size_t)r * lda + (k0 & 511) + skq;
            } else {
                const int rowc = row < M ? row : (M - 1);
                off = (size_t)rowc * lda + k0 + skq;
            }
            *(s8v*)&As[m * 40 + skq] = *(const s8v*)(A + off);
        }
        #pragma unroll
        for (int h = 0; h < 2; ++h) {
            const int n = sr + h * 32;
            *(s8v*)&Ws[n * 40 + skq] = *(const s8v*)(Wt + (size_t)(bn + n) * K + k0 + skq);
        }
        __syncthreads();
        s8v af[4], bfv[4];
        #pragma unroll
        for (int i = 0; i < 4; ++i) {
            af[i]  = *(const s8v*)&As[(mbase + i * 16 + l15) * 40 + quad * 8];
            bfv[i] = *(const s8v*)&Ws[(i * 16 + l15) * 40 + quad * 8];
        }
        #pragma unroll
        for (int mi = 0; mi < 4; ++mi)
            #pragma unroll
            for (int ni = 0; ni < 4; ++ni)
                acc[mi][ni] = __builtin_amdgcn_mfma_f32_16x16x32_bf16(
                    af[mi], bfv[ni], acc[mi][ni], 0, 0, 0);
    }

    const int f = *flagp;
    float bv[4];
    #pragma unroll
    for (int ni = 0; ni < 4; ++ni)
        bv[ni] = ldw(bias, boff0 + (unsigned)(bn + ni * 16 + l15), f);

    #pragma unroll
    for (int mi = 0; mi < 4; ++mi) {
        #pragma unroll
        for (int r = 0; r < 4; ++r) {
            const int row = bm + mbase + mi * 16 + quad * 4 + r;
            if (row < M) {
                #pragma unroll
                for (int ni = 0; ni < 4; ++ni) {
                    float o = acc[mi][ni][r] + bv[ni];
                    if (RELU) o = fmaxf(o, 0.f);
                    C[(size_t)row * ldc + bn + ni * 16 + l15] = __float2bfloat16(o);
                }
            }
        }
    }
}

// ---------------- fused tile attention (strided q/k/v) ----------------
// MODE 0: ProbSparse top-16. MODE 1: causal. MODE 2: plain cross.
template<int MODE>
__global__ __launch_bounds__(256) void fattn_k(
    bf16* __restrict__ q, const bf16* __restrict__ k, const bf16* __restrict__ v,
    int ldq, int ldkv, int Lq, int Lk)
{
    __shared__ short Qs[16 * 72];
    __shared__ short Ks[64 * 72];
    __shared__ float S[16 * 516];
    __shared__ float pw[16][16];
    __shared__ int   pidx[16][16];
    __shared__ float mrow[16];
    __shared__ float dinv[16];

    const int t = threadIdx.x;
    const int q0 = blockIdx.x * 16, h = blockIdx.y, b = blockIdx.z;
    const int lane = t & 63, wave = t >> 6;
    const int l15 = lane & 15, quad = lane >> 4;

    const int qv = (Lq - q0) < 16 ? (Lq - q0) : 16;

    const bf16* Kbase = k + (size_t)b * Lk * ldkv + h * DK;
    const bf16* Vbase = v + (size_t)b * Lk * ldkv + h * DK;
    bf16* Qbase = q + (size_t)(b * Lq + q0) * ldq + h * DK;

    const int kmax = (MODE == 1) ? (q0 + 16 < Lk ? q0 + 16 : Lk) : Lk;
    const int ntile = (kmax + 63) >> 6;
    const int kpad = ntile << 6;

    if (t < 128) {
        const int qr = t >> 3;
        const int qsrc = qr < qv ? qr : qv - 1;
        *(s8v*)&Qs[qr * 72 + (t & 7) * 8] =
            *(const s8v*)(Qbase + (size_t)qsrc * ldq + (t & 7) * 8);
    }

    // ---- phase 1: S = QK^T / 8 (+ masks), via MFMA ----
    for (int kt = 0; kt < ntile; ++kt) {
        __syncthreads();
        const int k0 = kt << 6;
        int srow = k0 + (t >> 2); if (srow >= Lk) srow = Lk - 1;
        const bf16* kp = Kbase + (size_t)srow * ldkv + (t & 3) * 16;
        *(s8v*)&Ks[(t >> 2) * 72 + (t & 3) * 16]     = *(const s8v*)kp;
        *(s8v*)&Ks[(t >> 2) * 72 + (t & 3) * 16 + 8] = *(const s8v*)(kp + 8);
        __syncthreads();
        const s8v a0 = *(const s8v*)&Qs[l15 * 72 + quad * 8];
        const s8v a1 = *(const s8v*)&Qs[l15 * 72 + 32 + quad * 8];
        const s8v b0 = *(const s8v*)&Ks[(wave * 16 + l15) * 72 + quad * 8];
        const s8v b1 = *(const s8v*)&Ks[(wave * 16 + l15) * 72 + 32 + quad * 8];
        f4v acc = {0.f, 0.f, 0.f, 0.f};
        acc = __builtin_amdgcn_mfma_f32_16x16x32_bf16(a0, b0, acc, 0, 0, 0);
        acc = __builtin_amdgcn_mfma_f32_16x16x32_bf16(a1, b1, acc, 0, 0, 0);
        const int colg = k0 + wave * 16 + l15;
        #pragma unroll
        for (int r = 0; r < 4; ++r) {
            const int qrow = quad * 4 + r;
            float s = acc[r] * 0.125f;
            if (colg >= Lk) s = -1e9f;
            if (MODE == 1 && colg > q0 + qrow) s = -1e9f;
            S[qrow * 516 + colg] = s;
        }
    }
    __syncthreads();

    // ---- phase 2 ----
    if (MODE == 0) {
        unsigned key[4][8];
        float mr[4], den[4];
        #pragma unroll
        for (int r = 0; r < 4; ++r) {
            const int row = wave * 4 + r;
            #pragma unroll
            for (int j = 0; j < 8; ++j) {
                const int col = lane + 64 * j;
                key[r][j] = (col < kpad)
                    ? ((f2ord(S[row * 516 + col]) & 0xFFFFFE00u) | (unsigned)col)
                    : 0u;
            }
            den[r] = 0.f;
            mr[r] = 0.f;
        }
        for (int it = 0; it < 16; ++it) {
            #pragma unroll
            for (int r = 0; r < 4; ++r) {
                unsigned mx = key[r][0];
                #pragma unroll
                for (int j = 1; j < 8; ++j) mx = mx > key[r][j] ? mx : key[r][j];
                #pragma unroll
                for (int off = 1; off < 64; off <<= 1) {
                    const unsigned o = __shfl_xor(mx, off);
                    mx = mx > o ? mx : o;
                }
                #pragma unroll
                for (int j = 0; j < 8; ++j) if (key[r][j] == mx) key[r][j] = 0u;
                const int col = (int)(mx & 511u);
                const int row = wave * 4 + r;
                const float sval = S[row * 516 + col];
                if (it == 0) mr[r] = sval;
                const float e = expf(sval - mr[r]);
                den[r] += e;
                if (lane == 0) { pw[row][it] = e; pidx[row][it] = col; }
            }
        }
        #pragma unroll
        for (int r = 0; r < 4; ++r)
            if (lane == 0) dinv[wave * 4 + r] = 1.f / den[r];
    } else {
        float mx[4];
        #pragma unroll
        for (int r = 0; r < 4; ++r) {
            const int row = wave * 4 + r;
            float lv = -INFINITY;
            #pragma unroll
            for (int j = 0; j < 8; ++j) {
                const int col = lane + 64 * j;
                if (col < kpad) lv = fmaxf(lv, S[row * 516 + col]);
            }
            mx[r] = lv;
        }
        #pragma unroll
        for (int off = 1; off < 64; off <<= 1) {
            #pragma unroll
            for (int r = 0; r < 4; ++r) mx[r] = fmaxf(mx[r], __shfl_xor(mx[r], off));
        }
        #pragma unroll
        for (int r = 0; r < 4; ++r)
            if (lane == 0) mrow[wave * 4 + r] = mx[r];
    }
    __syncthreads();

    const int row = t >> 4, c16 = t & 15;

    if (MODE != 0) {
        const float m = mrow[row];
        float part = 0.f;
        for (int j = 0; j < 32; ++j) {
            const int col = c16 + 16 * j;
            if (col < kpad) {
                const float w = expf(S[row * 516 + col] - m);
                S[row * 516 + col] = w;
                part += w;
            }
        }
        part += __shfl_xor(part, 1);
        part += __shfl_xor(part, 2);
        part += __shfl_xor(part, 4);
        part += __shfl_xor(part, 8);
        if (c16 == 0) dinv[row] = 1.f / part;
        __syncthreads();
    }

    // ---- phase 3: PV + store ----
    const float inv = dinv[row];
    float a0 = 0.f, a1 = 0.f, a2 = 0.f, a3 = 0.f;
    if (MODE == 0) {
        #pragma unroll
        for (int j = 0; j < 16; ++j) {
            const float w = pw[row][j];
            const int kk = pidx[row][j];
            const ushort4 u = *(const ushort4*)(Vbase + (size_t)kk * ldkv + c16 * 4);
            a0 += w * u2f(u.x); a1 += w * u2f(u.y);
            a2 += w * u2f(u.z); a3 += w * u2f(u.w);
        }
    } else {
        const int kend = (MODE == 1) ? (q0 + row + 1 < kmax ? q0 + row + 1 : kmax) : kmax;
        for (int k2 = 0; k2 < kend; ++k2) {
            const float w = S[row * 516 + k2];
            const ushort4 u = *(const ushort4*)(Vbase + (size_t)k2 * ldkv + c16 * 4);
            a0 += w * u2f(u.x); a1 += w * u2f(u.y);
            a2 += w * u2f(u.z); a3 += w * u2f(u.w);
        }
    }
    if (row < qv) {
        ushort4 o;
        { bf16 h0 = __float2bfloat16(a0 * inv); o.x = *(unsigned short*)&h0; }
        { bf16 h1 = __float2bfloat16(a1 * inv); o.y = *(unsigned short*)&h1; }
        { bf16 h2 = __float2bfloat16(a2 * inv); o.z = *(unsigned short*)&h2; }
        { bf16 h3 = __float2bfloat16(a3 * inv); o.w = *(unsigned short*)&h3; }
        *(ushort4*)(Qbase + (size_t)row * ldq + c16 * 4) = o;
    }
}

// ---------------- layernorm over D=512, optional residual; in-place safe ----------------
__global__ __launch_bounds__(256) void ln_off_k(
    const bf16* __restrict__ X, const bf16* __restrict__ R,
    const void* __restrict__ gb, unsigned goff,
    bf16* __restrict__ Out, const int* __restrict__ flagp)
{
    __shared__ float red[4];
    const int f = *flagp;
    const int t = threadIdx.x;
    const size_t base = (size_t)blockIdx.x * DM;
    float v0 = b2f(X[base + t]), v1 = b2f(X[base + t + 256]);
    if (R) { v0 += b2f(R[base + t]); v1 += b2f(R[base + t + 256]); }
    const float mean = block_sum256(v0 + v1, red) * (1.f / 512.f);
    const float d0 = v0 - mean, d1 = v1 - mean;
    const float var = block_sum256(d0 * d0 + d1 * d1, red) * (1.f / 512.f);
    const float rstd = rsqrtf(var + 1e-5f);
    Out[base + t]       = __float2bfloat16(d0 * rstd * ldw(gb, goff + t, f)       + ldw(gb, goff + 512 + t, f));
    Out[base + t + 256] = __float2bfloat16(d1 * rstd * ldw(gb, goff + t + 256, f) + ldw(gb, goff + 768 + t, f));
}

// ---------------- conv distill helpers ----------------
// conv weights w[o][c][j] (512,512,3) -> transposed GEMM layout wt[o][j*512+c]
__global__ __launch_bounds__(256) void convw_k(const void* __restrict__ w, unsigned woff,
                                               bf16* __restrict__ wt, int total,
                                               const int* __restrict__ flagp) {
    const int f = *flagp;
    int i = blockIdx.x * 256 + threadIdx.x;
    if (i >= total) return;
    const int o = i / 1536, rem = i % 1536;
    const int j = rem >> 9, c = rem & 511;
    wt[i] = __float2bfloat16(ldw(w, woff + (unsigned)(o * 512 + c) * 3 + j, f));
}

__global__ __launch_bounds__(256) void convidx_k(int* __restrict__ idx, int Lc, int L, int total) {
    int i = blockIdx.x * 256 + threadIdx.x;
    if (i >= total) return;
    const int j = i / (16 * Lc), mrem = i % (16 * Lc);
    const int b = mrem / Lc, l = mrem % Lc;
    int src = l + j - 2;
    src %= L; if (src < 0) src += L;
    idx[i] = b * L + src;
}

__global__ __launch_bounds__(256) void bnstat1_k(const bf16* __restrict__ Y, float* __restrict__ part, int M) {
    const int t = threadIdx.x;
    float s0 = 0.f, q0 = 0.f, s1 = 0.f, q1 = 0.f;
    for (int r = blockIdx.x; r < M; r += gridDim.x) {
        const ushort2 u = *reinterpret_cast<const ushort2*>(Y + (size_t)r * DM + t * 2);
        const float a = u2f(u.x), c = u2f(u.y);
        s0 += a; q0 += a * a;
        s1 += c; q1 += c * c;
    }
    float* p = part + (size_t)blockIdx.x * 1024;
    p[2 * t] = s0; p[2 * t + 1] = s1;
    p[512 + 2 * t] = q0; p[512 + 2 * t + 1] = q1;
}

__global__ __launch_bounds__(256) void bnstat2_k(const float* __restrict__ part, float* __restrict__ stats,
                                                 int nchunk, int M) {
    const int ch = blockIdx.x * 256 + threadIdx.x;
    if (ch >= 512) return;
    float S = 0.f, Qs = 0.f;
    for (int c = 0; c < nchunk; ++c) { S += part[c * 1024 + ch]; Qs += part[c * 1024 + 512 + ch]; }
    const float mean = S / (float)M;
    const float var = Qs / (float)M - mean * mean;
    stats[ch] = mean;
    stats[512 + ch] = fmaxf(var, 0.f);
}

__global__ __launch_bounds__(256) void bnpool_k(
    const bf16* __restrict__ Yc, const float* __restrict__ stats,
    const void* __restrict__ g, const void* __restrict__ bb, unsigned off,
    bf16* __restrict__ Out, int Lc, int Lout, int total, const int* __restrict__ flagp)
{
    const int f = *flagp;
    int i = blockIdx.x * 256 + threadIdx.x;
    if (i >= total) return;
    const int ch = i & 511;
    const int lp = (i >> 9) % Lout;
    const int b = i / (512 * Lout);
    const float mean = stats[ch], var = stats[512 + ch];
    const float sc = ldw(g, off + ch, f) * rsqrtf(var + 1e-5f);
    const float sh = ldw(bb, off + ch, f) - mean * sc;
    float mx = -INFINITY;
    const int l0 = 2 * lp - 1;
    #pragma unroll
    for (int d = 0; d < 3; ++d) {
        const int l = l0 + d;
        if (l >= 0 && l < Lc) {
            float v = b2f(Yc[((size_t)b * Lc + l) * DM + ch]) * sc + sh;
            v = v > 0.f ? v : expm1f(v);  // ELU
            mx = fmaxf(mx, v);
        }
    }
    Out[((size_t)b * Lout + lp) * DM + ch] = __float2bfloat16(mx);
}

// ---------------- final projection to CO=7, dtype-matched store ----------------
__global__ __launch_bounds__(256) void fc_k(
    const bf16* __restrict__ Yn, const void* __restrict__ fcw, const void* __restrict__ fcb,
    void* __restrict__ out, int total, const int* __restrict__ flagp)
{
    const int f = *flagp;
    int i = blockIdx.x * 256 + threadIdx.x;
    if (i >= total) return;
    const int r = i / 7, co = i % 7;
    const bf16* yr = Yn + (size_t)r * DM;
    float acc = ldw(fcb, co, f);
    for (int d = 0; d < DM; ++d) acc += b2f(yr[d]) * ldw(fcw, d * 7 + co, f);
    if (f) ((bf16*)out)[i] = __float2bfloat16(acc);
    else   ((float*)out)[i] = acc;
}

// =============================================================================
extern "C" void kernel_launch(void* const* d_in, const int* in_sizes, int n_in,
                              void* d_out, int out_size, void* d_ws, size_t ws_size,
                              hipStream_t stream)
{
    const void* x_enc      = d_in[0];
    const void* x_mark_enc = d_in[1];
    const void* x_dec      = d_in[2];
    const void* x_mark_dec = d_in[3];
    const void* enc_vw = d_in[4];
    const void* enc_vb = d_in[5];
    const void* enc_mw = d_in[6];
    const void* enc_mb = d_in[7];
    const void* dec_vw = d_in[8];
    const void* dec_vb = d_in[9];
    const void* dec_mw = d_in[10];
    const void* dec_mb = d_in[11];
    const void* eW    = d_in[12];
    const void* ebi   = d_in[13];
    const void* effw1 = d_in[14];
    const void* effb1 = d_in[15];
    const void* effw2 = d_in[16];
    const void* effb2 = d_in[17];
    const void* eln1  = d_in[18];
    const void* eln2  = d_in[19];
    const void* cw    = d_in[20];
    const void* cb    = d_in[21];
    const void* cbn_g = d_in[22];
    const void* cbn_b = d_in[23];
    const void* enc_norm = d_in[24];
    const void* dsW   = d_in[25];
    const void* dsb   = d_in[26];
    const void* dcW   = d_in[27];
    const void* dcb   = d_in[28];
    const void* dffw1 = d_in[29];
    const void* dffb1 = d_in[30];
    const void* dffw2 = d_in[31];
    const void* dffb2 = d_in[32];
    const void* dln   = d_in[33];
    const void* dec_norm = d_in[34];
    const void* fcw   = d_in[35];
    const void* fcb   = d_in[36];

    // ---- workspace layout (~78.3 MiB; 111 MiB known-safe from round 1) ----
    // X    [0, 8M)      : encoder acts; MEM [2080][512] + Yd [4096][512] in decoder phase
    // QKV  [8M, 32M)    : fused QKV buffer (up to [8192][1536]); conv out; cross CQ/CKV
    // OUT  [32M, 40M)   : O-proj / FFN2 dest
    // WT   [40M, 44M)   : transposed weights (QKVO 2M / W1T+W2T 4M / convWt 1.5M)
    // HID  [44M, 78M)   : FFN hidden (up to [8192][2048])
    // misc [78M, ...)   : IDX, PART, STATS, FLAG
    char* wsp = (char*)d_ws;
    bf16* X    = (bf16*)wsp;
    bf16* QKV  = (bf16*)(wsp + ((size_t)8 << 20));
    bf16* OUT  = (bf16*)(wsp + ((size_t)32 << 20));
    bf16* WT   = (bf16*)(wsp + ((size_t)40 << 20));
    bf16* HID  = (bf16*)(wsp + ((size_t)44 << 20));
    int*   IDX  = (int*)(wsp + ((size_t)78 << 20));
    float* PART = (float*)(wsp + ((size_t)78 << 20) + 262144);
    float* STATS= (float*)(wsp + ((size_t)78 << 20) + 262144 + 131072);
    int*   FLAG = (int*)(wsp + ((size_t)78 << 20) + 262144 + 131072 + 4096);
    bf16* MEMb = X;                                               // [2080][512]
    bf16* Yd   = (bf16*)(wsp + (size_t)16 * 130 * 512 * 2);       // [4096][512]

    auto cdiv = [](int a, int b) { return (a + b - 1) / b; };
    // 128x128 GEMM (256 thr)
    auto gemm = [&](const bf16* A, const bf16* Wt, const void* bias, unsigned boff,
                    bf16* C, int M, int N, int K, int lda, int ldc, bool relu) {
        dim3 g(N / 128, cdiv(M, 128));
        if (relu) mgemm_k<false, true><<<g, 256, 0, stream>>>(
            (const short*)A, nullptr, (const short*)Wt, bias, boff, C, M, N, K, lda, ldc, FLAG);
        else      mgemm_k<false, false><<<g, 256, 0, stream>>>(
            (const short*)A, nullptr, (const short*)Wt, bias, boff, C, M, N, K, lda, ldc, FLAG);
    };
    // 128x64 GEMM (128 thr) for N=512-class
    auto gemm64 = [&](const bf16* A, const bf16* Wt, const void* bias, unsigned boff,
                      bf16* C, int M, int N, int K, int lda, int ldc) {
        dim3 g(N / 64, cdiv(M, 128));
        mgemm64_k<false, false><<<g, 128, 0, stream>>>(
            (const short*)A, nullptr, (const short*)Wt, bias, boff, C, M, N, K, lda, ldc, FLAG);
    };
    auto transp = [&](const void* W, unsigned off, unsigned zstride, int nz,
                      bf16* out, int K, int N) {
        transp_k<<<dim3(N / 32, K / 32, nz), 256, 0, stream>>>(W, off, zstride, out, K, N, FLAG);
    };

    // dtype sniff on x_mark_enc
    sniff_k<<<1, 256, 0, stream>>>((const unsigned*)x_mark_enc, 16384, FLAG);

    // ---- encoder embedding ----
    embed_k<<<cdiv(16 * 512 * 512, 256), 256, 0, stream>>>(
        x_enc, enc_vw, enc_vb, x_mark_enc, enc_mw, enc_mb, X, 16 * 512, 7, 4, FLAG);

    // ---- encoder ----
    int L = 512;
    for (int i = 0; i < 3; ++i) {
        const int rows = 16 * L;
        const unsigned W0 = (unsigned)i * 4u * 262144u;
        const unsigned b0 = (unsigned)i * 4u * 512u;
        // QKVO weights -> WT rows [0,2048)
        transp(eW, W0, 262144u, 4, WT, 512, 512);
        // fused QKV: N=1536 into strided QKV buffer
        gemm(X, WT, ebi, b0, QKV, rows, 1536, 512, 512, 1536, false);
        fattn_k<0><<<dim3(cdiv(L, 16), 8, 16), 256, 0, stream>>>(
            QKV, QKV + 512, QKV + 1024, 1536, 1536, L, L);
        // O-proj (Wt rows [1536,2048))
        gemm64(QKV, WT + 1536 * 512, ebi, b0 + 1536u, OUT, rows, 512, 512, 1536, 512);
        ln_off_k<<<rows, 256, 0, stream>>>(X, OUT, eln1, (unsigned)i * 1024u, X, FLAG);

        transp(effw1, (unsigned)i * 1048576u, 0u, 1, WT, 512, 2048);             // W1T
        transp(effw2, (unsigned)i * 1048576u, 0u, 1, WT + 1048576, 2048, 512);   // W2T
        gemm(X, WT, effb1, (unsigned)i * 2048u, HID, rows, 2048, 512, 512, 2048, true);
        gemm64(HID, WT + 1048576, effb2, (unsigned)i * 512u, OUT, rows, 512, 2048, 2048, 512);
        ln_off_k<<<rows, 256, 0, stream>>>(X, OUT, eln2, (unsigned)i * 1024u, X, FLAG);

        if (i < 2) {
            convw_k<<<cdiv(786432, 256), 256, 0, stream>>>(cw, (unsigned)i * 786432u, WT, 786432, FLAG);
            const int Lc = L + 2, Mc = 16 * Lc;
            convidx_k<<<cdiv(3 * Mc, 256), 256, 0, stream>>>(IDX, Lc, L, 3 * Mc);
            mgemm64_k<true, false><<<dim3(8, cdiv(Mc, 128)), 128, 0, stream>>>(
                (const short*)X, IDX, (const short*)WT, cb, (unsigned)i * 512u,
                QKV, Mc, 512, 1536, 512, 512, FLAG);
            bnstat1_k<<<32, 256, 0, stream>>>(QKV, PART, Mc);
            bnstat2_k<<<2, 256, 0, stream>>>(PART, STATS, 32, Mc);
            const int Lout = (L + 1) / 2 + 1;   // 514->257, 259->130
            const int tot = 16 * Lout * 512;
            bnpool_k<<<cdiv(tot, 256), 256, 0, stream>>>(
                QKV, STATS, cbn_g, cbn_b, (unsigned)i * 512u, X, Lc, Lout, tot, FLAG);
            L = Lout;
        }
    }
    const int Lm = L;  // 130
    ln_off_k<<<16 * Lm, 256, 0, stream>>>(X, nullptr, enc_norm, 0u, MEMb, FLAG);

    // ---- decoder embedding ----
    const int rowsD = 16 * 256;
    embed_k<<<cdiv(rowsD * 512, 256), 256, 0, stream>>>(
        x_dec, dec_vw, dec_vb, x_mark_dec, dec_mw, dec_mb, Yd, rowsD, 7, 4, FLAG);

    // ---- decoder ----
    bf16* CQ  = QKV;                       // [4096][512]
    bf16* CKV = QKV + (size_t)4096 * 512;  // [2080][1024]
    for (int i = 0; i < 2; ++i) {
        const unsigned W0 = (unsigned)i * 4u * 262144u;
        const unsigned b0 = (unsigned)i * 4u * 512u;
        // self-attention
        transp(dsW, W0, 262144u, 4, WT, 512, 512);
        gemm(Yd, WT, dsb, b0, QKV, rowsD, 1536, 512, 512, 1536, false);
        fattn_k<1><<<dim3(16, 8, 16), 256, 0, stream>>>(
            QKV, QKV + 512, QKV + 1024, 1536, 1536, 256, 256);
        gemm64(QKV, WT + 1536 * 512, dsb, b0 + 1536u, OUT, rowsD, 512, 512, 1536, 512);
        ln_off_k<<<rowsD, 256, 0, stream>>>(Yd, OUT, dln, (unsigned)(i * 3 + 0) * 1024u, Yd, FLAG);

        // cross-attention
        transp(dcW, W0, 262144u, 4, WT, 512, 512);
        gemm64(Yd, WT, dcb, b0, CQ, rowsD, 512, 512, 512, 512);
        gemm(MEMb, WT + 512 * 512, dcb, b0 + 512u, CKV, 16 * Lm, 1024, 512, 512, 1024, false);
        fattn_k<2><<<dim3(16, 8, 16), 256, 0, stream>>>(
            CQ, CKV, CKV + 512, 512, 1024, 256, Lm);
        gemm64(CQ, WT + 1536 * 512, dcb, b0 + 1536u, OUT, rowsD, 512, 512, 512, 512);
        ln_off_k<<<rowsD, 256, 0, stream>>>(Yd, OUT, dln, (unsigned)(i * 3 + 1) * 1024u, Yd, FLAG);

        // FFN
        transp(dffw1, (unsigned)i * 1048576u, 0u, 1, WT, 512, 2048);
        transp(dffw2, (unsigned)i * 1048576u, 0u, 1, WT + 1048576, 2048, 512);
        gemm(Yd, WT, dffb1, (unsigned)i * 2048u, HID, rowsD, 2048, 512, 512, 2048, true);
        gemm64(HID, WT + 1048576, dffb2, (unsigned)i * 512u, OUT, rowsD, 512, 2048, 2048, 512);
        ln_off_k<<<rowsD, 256, 0, stream>>>(Yd, OUT, dln, (unsigned)(i * 3 + 2) * 1024u, Yd, FLAG);
    }

    ln_off_k<<<rowsD, 256, 0, stream>>>(Yd, nullptr, dec_norm, 0u, OUT, FLAG);
    fc_k<<<cdiv(rowsD * 7, 256), 256, 0, stream>>>(OUT, fcw, fcb, d_out, rowsD * 7, FLAG);
}

// Round 8
// 1921.762 us; speedup vs baseline: 6.6502x; 1.0553x over previous
//
#include <hip/hip_runtime.h>
#include <hip/hip_bf16.h>

// Informer forward, MI355X. Round 8: GEMM staging via __builtin_amdgcn_global_load_lds
// (width=16, unpadded [rows][32]-short LDS tiles, conflict-neutral b128 frag reads) and
// one-time batched weight-transpose prologue (weights constant across the launch).
// FFN hidden aliases dead QKV region; ws ~90 MB (111 MB empirically tolerated in round 1).
// Retained: dtype sniffer, fused QKV (N=1536), mgemm64 for N=512, packed-key top-16 fattn.
// Round 7: passed, absmax 0.0117, 2028 us; GEMM chain ~115 TF was the bottleneck.
// B=16, LE=512, LD=256, D=512, H=8, dk=64, DFF=2048, NE=3, ND=2, TOPK=16.
// Encoder lengths: 512 -> conv(514)/pool -> 257 -> conv(259)/pool -> 130.

#define DM 512
#define DK 64

using bf16 = __hip_bfloat16;
typedef short s8v __attribute__((ext_vector_type(8)));
typedef float f4v __attribute__((ext_vector_type(4)));

__device__ inline float b2f(bf16 x) { return __bfloat162float(x); }
__device__ inline float u2f(unsigned short u) { return __uint_as_float((unsigned)u << 16); }

// flag f: 1 = raw inputs are bf16, 0 = raw inputs are fp32. idx in ELEMENTS.
__device__ inline float ldw(const void* p, unsigned i, int f) {
    return f ? b2f(((const bf16*)p)[i]) : ((const float*)p)[i];
}

// order-preserving float->u32 (monotonic)
__device__ inline unsigned f2ord(float s) {
    unsigned u = __float_as_uint(s);
    return u ^ ((unsigned)((int)u >> 31) | 0x80000000u);
}

// async global->LDS, 16 B per lane; lds dst must be wave-uniform (lane i lands at dst+16*i)
__device__ inline void gl_lds16(const short* g, short* l) {
    __builtin_amdgcn_global_load_lds(
        (const __attribute__((address_space(1))) unsigned int*)g,
        (__attribute__((address_space(3))) unsigned int*)l,
        16, 0, 0);
}

// ---------------- dtype sniffer ----------------
__global__ __launch_bounds__(256) void sniff_k(const unsigned* __restrict__ x, int nwords,
                                               int* __restrict__ flag) {
    __shared__ int red[4];
    const int t = threadIdx.x;
    int c = 0;
    for (int i = t; i < nwords; i += 256) c += ((x[i] & 0x7F80u) == 0x3F80u) ? 1 : 0;
    #pragma unroll
    for (int o = 32; o > 0; o >>= 1) c += __shfl_down(c, o);
    __syncthreads();
    if ((t & 63) == 0) red[t >> 6] = c;
    __syncthreads();
    if (t == 0) flag[0] = (red[0] + red[1] + red[2] + red[3] > nwords / 20) ? 1 : 0;
}

// ---------------- reductions (blockDim == 256) ----------------
__device__ inline float block_sum256(float v, float* red) {
    #pragma unroll
    for (int o = 32; o > 0; o >>= 1) v += __shfl_down(v, o);
    __syncthreads();
    if ((threadIdx.x & 63) == 0) red[threadIdx.x >> 6] = v;
    __syncthreads();
    return red[0] + red[1] + red[2] + red[3];
}

// ---------------- embedding ----------------
__global__ __launch_bounds__(256) void embed_k(
    const void* __restrict__ xv, const void* __restrict__ vw, const void* __restrict__ vb,
    const void* __restrict__ xm, const void* __restrict__ mw, const void* __restrict__ mb,
    bf16* __restrict__ Out, int rows, int Cv, int Cm, const int* __restrict__ flagp)
{
    const int f = *flagp;
    int i = blockIdx.x * 256 + threadIdx.x;
    if (i >= rows * DM) return;
    const int r = i >> 9, d = i & 511;
    float acc = ldw(vb, d, f) + ldw(mb, d, f);
    for (int c = 0; c < Cv; ++c) acc += ldw(xv, r * Cv + c, f) * ldw(vw, c * DM + d, f);
    for (int c = 0; c < Cm; ++c) acc += ldw(xm, r * Cm + c, f) * ldw(mw, c * DM + d, f);
    Out[i] = __float2bfloat16(acc);
}

// ---------------- weight transpose: raw [K][N] -> bf16 [N][K]; z batches sub-mats ----------------
__global__ __launch_bounds__(256) void transp_k(
    const void* __restrict__ W, unsigned off, unsigned zstride, bf16* __restrict__ out,
    int K, int N, const int* __restrict__ flagp)
{
    __shared__ float tile[32][33];
    const int f = *flagp;
    const unsigned zo = blockIdx.z * zstride;
    const int t = threadIdx.x;
    const int tx = t & 31, ty = t >> 5;               // 32 x 8
    const int n0 = blockIdx.x * 32, k0 = blockIdx.y * 32;
    #pragma unroll
    for (int i = 0; i < 4; ++i)
        tile[ty + 8 * i][tx] = ldw(W, off + zo + (unsigned)(k0 + ty + 8 * i) * N + n0 + tx, f);
    __syncthreads();
    #pragma unroll
    for (int i = 0; i < 4; ++i)
        out[(size_t)zo + (size_t)(n0 + ty + 8 * i) * K + k0 + tx] = __float2bfloat16(tile[tx][ty + 8 * i]);
}

// ---------------- MFMA GEMM 128x128 (256 thr): C = A[M,K]@Wt[N,K]^T + bias ----------------
// Staging via global_load_lds (16 B/lane), unpadded [row][32]-short LDS tiles.
template<bool G3, bool RELU>
__global__ __launch_bounds__(256) void mgemm_k(
    const short* __restrict__ A, const int* __restrict__ ridx,
    const short* __restrict__ Wt,
    const void* __restrict__ bias, unsigned boff0,
    bf16* __restrict__ C, int M, int N, int K, int lda, int ldc,
    const int* __restrict__ flagp)
{
    __shared__ short As[128 * 32];
    __shared__ short Ws[128 * 32];
    const int t = threadIdx.x;
    const int bm = blockIdx.y * 128, bn = blockIdx.x * 128;
    const int lane = t & 63, wave = t >> 6;
    const int mbase = (wave >> 1) * 64, nbase = (wave & 1) * 64;
    const int l15 = lane & 15, quad = lane >> 4;
    const int lrow = lane >> 2, lk = (lane & 3) * 8;

    f4v acc[4][4] = {};

    for (int k0 = 0; k0 < K; k0 += 32) {
        __syncthreads();
        #pragma unroll
        for (int j = 0; j < 2; ++j) {
            const int rb = wave * 32 + j * 16;
            const int row = bm + rb + lrow;
            const int rowc = row < M ? row : M - 1;
            const short* g;
            if (G3) {
                const int r = ridx[(k0 >> 9) * M + rowc];
                g = A + (size_t)r * lda + (k0 & 511) + lk;
            } else {
                g = A + (size_t)rowc * lda + k0 + lk;
            }
            gl_lds16(g, &As[rb * 32]);
        }
        #pragma unroll
        for (int j = 0; j < 2; ++j) {
            const int nb = wave * 32 + j * 16;
            gl_lds16(Wt + (size_t)(bn + nb + lrow) * K + k0 + lk, &Ws[nb * 32]);
        }
        __syncthreads();
        s8v af[4], bfv[4];
        #pragma unroll
        for (int i = 0; i < 4; ++i) {
            af[i]  = *(const s8v*)&As[(mbase + i * 16 + l15) * 32 + quad * 8];
            bfv[i] = *(const s8v*)&Ws[(nbase + i * 16 + l15) * 32 + quad * 8];
        }
        #pragma unroll
        for (int mi = 0; mi < 4; ++mi)
            #pragma unroll
            for (int ni = 0; ni < 4; ++ni)
                acc[mi][ni] = __builtin_amdgcn_mfma_f32_16x16x32_bf16(
                    af[mi], bfv[ni], acc[mi][ni], 0, 0, 0);
    }

    const int f = *flagp;
    float bv[4];
    #pragma unroll
    for (int ni = 0; ni < 4; ++ni)
        bv[ni] = ldw(bias, boff0 + (unsigned)(bn + nbase + ni * 16 + l15), f);

    #pragma unroll
    for (int mi = 0; mi < 4; ++mi) {
        #pragma unroll
        for (int r = 0; r < 4; ++r) {
            const int row = bm + mbase + mi * 16 + quad * 4 + r;
            if (row < M) {
                #pragma unroll
                for (int ni = 0; ni < 4; ++ni) {
                    float o = acc[mi][ni][r] + bv[ni];
                    if (RELU) o = fmaxf(o, 0.f);
                    C[(size_t)row * ldc + bn + nbase + ni * 16 + l15] = __float2bfloat16(o);
                }
            }
        }
    }
}

// ---------------- MFMA GEMM 128x64 (128 thr, 2 waves): for N=512-class GEMMs ----------------
template<bool G3, bool RELU>
__global__ __launch_bounds__(128) void mgemm64_k(
    const short* __restrict__ A, const int* __restrict__ ridx,
    const short* __restrict__ Wt,
    const void* __restrict__ bias, unsigned boff0,
    bf16* __restrict__ C, int M, int N, int K, int lda, int ldc,
    const int* __restrict__ flagp)
{
    __shared__ short As[128 * 32];
    __shared__ short Ws[64 * 32];
    const int t = threadIdx.x;
    const int bm = blockIdx.y * 128, bn = blockIdx.x * 64;
    const int lane = t & 63, wave = t >> 6;
    const int mbase = wave * 64;
    const int l15 = lane & 15, quad = lane >> 4;
    const int lrow = lane >> 2, lk = (lane & 3) * 8;

    f4v acc[4][4] = {};

    for (int k0 = 0; k0 < K; k0 += 32) {
        __syncthreads();
        #pragma unroll
        for (int j = 0; j < 4; ++j) {
            const int rb = wave * 64 + j * 16;
            const int row = bm + rb + lrow;
            const int rowc = row < M ? row : M - 1;
            const short* g;
            if (G3) {
                const int r = ridx[(k0 >> 9) * M + rowc];
                g = A + (size_t)r * lda + (k0 & 511) + lk;
            } else {
                g = A + (size_t)rowc * lda + k0 + lk;
            }
            gl_lds16(g, &As[rb * 32]);
        }
        #pragma unroll
        for (int j = 0; j < 2; ++j) {
            const int nb = wave * 32 + j * 16;
            gl_lds16(Wt + (size_t)(bn + nb + lrow) * K + k0 + lk, &Ws[nb * 32]);
        }
        __syncthreads();
        s8v af[4], bfv[4];
        #pragma unroll
        for (int i = 0; i < 4; ++i) {
            af[i]  = *(const s8v*)&As[(mbase + i * 16 + l15) * 32 + quad * 8];
            bfv[i] = *(const s8v*)&Ws[(i * 16 + l15) * 32 + quad * 8];
        }
        #pragma unroll
        for (int mi = 0; mi < 4; ++mi)
            #pragma unroll
            for (int ni = 0; ni < 4; ++ni)
                acc[mi][ni] = __builtin_amdgcn_mfma_f32_16x16x32_bf16(
                    af[mi], bfv[ni], acc[mi][ni], 0, 0, 0);
    }

    const int f = *flagp;
    float bv[4];
    #pragma unroll
    for (int ni = 0; ni < 4; ++ni)
        bv[ni] = ldw(bias, boff0 + (unsigned)(bn + ni * 16 + l15), f);

    #pragma unroll
    for (int mi = 0; mi < 4; ++mi) {
        #pragma unroll
        for (int r = 0; r < 4; ++r) {
            const int row = bm + mbase + mi * 16 + quad * 4 + r;
            if (row < M) {
                #pragma unroll
                for (int ni = 0; ni < 4; ++ni) {
                    float o = acc[mi][ni][r] + bv[ni];
                    if (RELU) o = fmaxf(o, 0.f);
                    C[(size_t)row * ldc + bn + ni * 16 + l15] = __float2bfloat16(o);
                }
            }
        }
    }
}

// ---------------- fused tile attention (strided q/k/v) ----------------
// MODE 0: ProbSparse top-16. MODE 1: causal. MODE 2: plain cross.
template<int MODE>
__global__ __launch_bounds__(256) void fattn_k(
    bf16* __restrict__ q, const bf16* __restrict__ k, const bf16* __restrict__ v,
    int ldq, int ldkv, int Lq, int Lk)
{
    __shared__ short Qs[16 * 72];
    __shared__ short Ks[64 * 72];
    __shared__ float S[16 * 516];
    __shared__ float pw[16][16];
    __shared__ int   pidx[16][16];
    __shared__ float mrow[16];
    __shared__ float dinv[16];

    const int t = threadIdx.x;
    const int q0 = blockIdx.x * 16, h = blockIdx.y, b = blockIdx.z;
    const int lane = t & 63, wave = t >> 6;
    const int l15 = lane & 15, quad = lane >> 4;

    const int qv = (Lq - q0) < 16 ? (Lq - q0) : 16;

    const bf16* Kbase = k + (size_t)b * Lk * ldkv + h * DK;
    const bf16* Vbase = v + (size_t)b * Lk * ldkv + h * DK;
    bf16* Qbase = q + (size_t)(b * Lq + q0) * ldq + h * DK;

    const int kmax = (MODE == 1) ? (q0 + 16 < Lk ? q0 + 16 : Lk) : Lk;
    const int ntile = (kmax + 63) >> 6;
    const int kpad = ntile << 6;

    if (t < 128) {
        const int qr = t >> 3;
        const int qsrc = qr < qv ? qr : qv - 1;
        *(s8v*)&Qs[qr * 72 + (t & 7) * 8] =
            *(const s8v*)(Qbase + (size_t)qsrc * ldq + (t & 7) * 8);
    }

    // ---- phase 1: S = QK^T / 8 (+ masks), via MFMA ----
    for (int kt = 0; kt < ntile; ++kt) {
        __syncthreads();
        const int k0 = kt << 6;
        int srow = k0 + (t >> 2); if (srow >= Lk) srow = Lk - 1;
        const bf16* kp = Kbase + (size_t)srow * ldkv + (t & 3) * 16;
        *(s8v*)&Ks[(t >> 2) * 72 + (t & 3) * 16]     = *(const s8v*)kp;
        *(s8v*)&Ks[(t >> 2) * 72 + (t & 3) * 16 + 8] = *(const s8v*)(kp + 8);
        __syncthreads();
        const s8v a0 = *(const s8v*)&Qs[l15 * 72 + quad * 8];
        const s8v a1 = *(const s8v*)&Qs[l15 * 72 + 32 + quad * 8];
        const s8v b0 = *(const s8v*)&Ks[(wave * 16 + l15) * 72 + quad * 8];
        const s8v b1 = *(const s8v*)&Ks[(wave * 16 + l15) * 72 + 32 + quad * 8];
        f4v acc = {0.f, 0.f, 0.f, 0.f};
        acc = __builtin_amdgcn_mfma_f32_16x16x32_bf16(a0, b0, acc, 0, 0, 0);
        acc = __builtin_amdgcn_mfma_f32_16x16x32_bf16(a1, b1, acc, 0, 0, 0);
        const int colg = k0 + wave * 16 + l15;
        #pragma unroll
        for (int r = 0; r < 4; ++r) {
            const int qrow = quad * 4 + r;
            float s = acc[r] * 0.125f;
            if (colg >= Lk) s = -1e9f;
            if (MODE == 1 && colg > q0 + qrow) s = -1e9f;
            S[qrow * 516 + colg] = s;
        }
    }
    __syncthreads();

    // ---- phase 2 ----
    if (MODE == 0) {
        unsigned key[4][8];
        float mr[4], den[4];
        #pragma unroll
        for (int r = 0; r < 4; ++r) {
            const int row = wave * 4 + r;
            #pragma unroll
            for (int j = 0; j < 8; ++j) {
                const int col = lane + 64 * j;
                key[r][j] = (col < kpad)
                    ? ((f2ord(S[row * 516 + col]) & 0xFFFFFE00u) | (unsigned)col)
                    : 0u;
            }
            den[r] = 0.f;
            mr[r] = 0.f;
        }
        for (int it = 0; it < 16; ++it) {
            #pragma unroll
            for (int r = 0; r < 4; ++r) {
                unsigned mx = key[r][0];
                #pragma unroll
                for (int j = 1; j < 8; ++j) mx = mx > key[r][j] ? mx : key[r][j];
                #pragma unroll
                for (int off = 1; off < 64; off <<= 1) {
                    const unsigned o = __shfl_xor(mx, off);
                    mx = mx > o ? mx : o;
                }
                #pragma unroll
                for (int j = 0; j < 8; ++j) if (key[r][j] == mx) key[r][j] = 0u;
                const int col = (int)(mx & 511u);
                const int row = wave * 4 + r;
                const float sval = S[row * 516 + col];
                if (it == 0) mr[r] = sval;
                const float e = expf(sval - mr[r]);
                den[r] += e;
                if (lane == 0) { pw[row][it] = e; pidx[row][it] = col; }
            }
        }
        #pragma unroll
        for (int r = 0; r < 4; ++r)
            if (lane == 0) dinv[wave * 4 + r] = 1.f / den[r];
    } else {
        float mx[4];
        #pragma unroll
        for (int r = 0; r < 4; ++r) {
            const int row = wave * 4 + r;
            float lv = -INFINITY;
            #pragma unroll
            for (int j = 0; j < 8; ++j) {
                const int col = lane + 64 * j;
                if (col < kpad) lv = fmaxf(lv, S[row * 516 + col]);
            }
            mx[r] = lv;
        }
        #pragma unroll
        for (int off = 1; off < 64; off <<= 1) {
            #pragma unroll
            for (int r = 0; r < 4; ++r) mx[r] = fmaxf(mx[r], __shfl_xor(mx[r], off));
        }
        #pragma unroll
        for (int r = 0; r < 4; ++r)
            if (lane == 0) mrow[wave * 4 + r] = mx[r];
    }
    __syncthreads();

    const int row = t >> 4, c16 = t & 15;

    if (MODE != 0) {
        const float m = mrow[row];
        float part = 0.f;
        for (int j = 0; j < 32; ++j) {
            const int col = c16 + 16 * j;
            if (col < kpad) {
                const float w = expf(S[row * 516 + col] - m);
                S[row * 516 + col] = w;
                part += w;
            }
        }
        part += __shfl_xor(part, 1);
        part += __shfl_xor(part, 2);
        part += __shfl_xor(part, 4);
        part += __shfl_xor(part, 8);
        if (c16 == 0) dinv[row] = 1.f / part;
        __syncthreads();
    }

    // ---- phase 3: PV + store ----
    const float inv = dinv[row];
    float a0 = 0.f, a1 = 0.f, a2 = 0.f, a3 = 0.f;
    if (MODE == 0) {
        #pragma unroll
        for (int j = 0; j < 16; ++j) {
            const float w = pw[row][j];
            const int kk = pidx[row][j];
            const ushort4 u = *(const ushort4*)(Vbase + (size_t)kk * ldkv + c16 * 4);
            a0 += w * u2f(u.x); a1 += w * u2f(u.y);
            a2 += w * u2f(u.z); a3 += w * u2f(u.w);
        }
    } else {
        const int kend = (MODE == 1) ? (q0 + row + 1 < kmax ? q0 + row + 1 : kmax) : kmax;
        for (int k2 = 0; k2 < kend; ++k2) {
            const float w = S[row * 516 + k2];
            const ushort4 u = *(const ushort4*)(Vbase + (size_t)k2 * ldkv + c16 * 4);
            a0 += w * u2f(u.x); a1 += w * u2f(u.y);
            a2 += w * u2f(u.z); a3 += w * u2f(u.w);
        }
    }
    if (row < qv) {
        ushort4 o;
        { bf16 h0 = __float2bfloat16(a0 * inv); o.x = *(unsigned short*)&h0; }
        { bf16 h1 = __float2bfloat16(a1 * inv); o.y = *(unsigned short*)&h1; }
        { bf16 h2 = __float2bfloat16(a2 * inv); o.z = *(unsigned short*)&h2; }
        { bf16 h3 = __float2bfloat16(a3 * inv); o.w = *(unsigned short*)&h3; }
        *(ushort4*)(Qbase + (size_t)row * ldq + c16 * 4) = o;
    }
}

// ---------------- layernorm over D=512, optional residual; in-place safe ----------------
__global__ __launch_bounds__(256) void ln_off_k(
    const bf16* __restrict__ X, const bf16* __restrict__ R,
    const void* __restrict__ gb, unsigned goff,
    bf16* __restrict__ Out, const int* __restrict__ flagp)
{
    __shared__ float red[4];
    const int f = *flagp;
    const int t = threadIdx.x;
    const size_t base = (size_t)blockIdx.x * DM;
    float v0 = b2f(X[base + t]), v1 = b2f(X[base + t + 256]);
    if (R) { v0 += b2f(R[base + t]); v1 += b2f(R[base + t + 256]); }
    const float mean = block_sum256(v0 + v1, red) * (1.f / 512.f);
    const float d0 = v0 - mean, d1 = v1 - mean;
    const float var = block_sum256(d0 * d0 + d1 * d1, red) * (1.f / 512.f);
    const float rstd = rsqrtf(var + 1e-5f);
    Out[base + t]       = __float2bfloat16(d0 * rstd * ldw(gb, goff + t, f)       + ldw(gb, goff + 512 + t, f));
    Out[base + t + 256] = __float2bfloat16(d1 * rstd * ldw(gb, goff + t + 256, f) + ldw(gb, goff + 768 + t, f));
}

// ---------------- conv distill helpers ----------------
// conv weights w[2][o][c][j] -> transposed GEMM layout wt[layer][o][j*512+c]
__global__ __launch_bounds__(256) void convw_k(const void* __restrict__ w,
                                               bf16* __restrict__ wt, int total,
                                               const int* __restrict__ flagp) {
    const int f = *flagp;
    int i = blockIdx.x * 256 + threadIdx.x;
    if (i >= total) return;
    const int layer = i / 786432, rem2 = i % 786432;
    const int o = rem2 / 1536, rem = rem2 % 1536;
    const int j = rem >> 9, c = rem & 511;
    wt[i] = __float2bfloat16(ldw(w, (unsigned)layer * 786432u + (unsigned)(o * 512 + c) * 3 + j, f));
}

__global__ __launch_bounds__(256) void convidx_k(int* __restrict__ idx, int Lc, int L, int total) {
    int i = blockIdx.x * 256 + threadIdx.x;
    if (i >= total) return;
    const int j = i / (16 * Lc), mrem = i % (16 * Lc);
    const int b = mrem / Lc, l = mrem % Lc;
    int src = l + j - 2;
    src %= L; if (src < 0) src += L;
    idx[i] = b * L + src;
}

__global__ __launch_bounds__(256) void bnstat1_k(const bf16* __restrict__ Y, float* __restrict__ part, int M) {
    const int t = threadIdx.x;
    float s0 = 0.f, q0 = 0.f, s1 = 0.f, q1 = 0.f;
    for (int r = blockIdx.x; r < M; r += gridDim.x) {
        const ushort2 u = *reinterpret_cast<const ushort2*>(Y + (size_t)r * DM + t * 2);
        const float a = u2f(u.x), c = u2f(u.y);
        s0 += a; q0 += a * a;
        s1 += c; q1 += c * c;
    }
    float* p = part + (size_t)blockIdx.x * 1024;
    p[2 * t] = s0; p[2 * t + 1] = s1;
    p[512 + 2 * t] = q0; p[512 + 2 * t + 1] = q1;
}

__global__ __launch_bounds__(256) void bnstat2_k(const float* __restrict__ part, float* __restrict__ stats,
                                                 int nchunk, int M) {
    const int ch = blockIdx.x * 256 + threadIdx.x;
    if (ch >= 512) return;
    float S = 0.f, Qs = 0.f;
    for (int c = 0; c < nchunk; ++c) { S += part[c * 1024 + ch]; Qs += part[c * 1024 + 512 + ch]; }
    const float mean = S / (float)M;
    const float var = Qs / (float)M - mean * mean;
    stats[ch] = mean;
    stats[512 + ch] = fmaxf(var, 0.f);
}

__global__ __launch_bounds__(256) void bnpool_k(
    const bf16* __restrict__ Yc, const float* __restrict__ stats,
    const void* __restrict__ g, const void* __restrict__ bb, unsigned off,
    bf16* __restrict__ Out, int Lc, int Lout, int total, const int* __restrict__ flagp)
{
    const int f = *flagp;
    int i = blockIdx.x * 256 + threadIdx.x;
    if (i >= total) return;
    const int ch = i & 511;
    const int lp = (i >> 9) % Lout;
    const int b = i / (512 * Lout);
    const float mean = stats[ch], var = stats[512 + ch];
    const float sc = ldw(g, off + ch, f) * rsqrtf(var + 1e-5f);
    const float sh = ldw(bb, off + ch, f) - mean * sc;
    float mx = -INFINITY;
    const int l0 = 2 * lp - 1;
    #pragma unroll
    for (int d = 0; d < 3; ++d) {
        const int l = l0 + d;
        if (l >= 0 && l < Lc) {
            float v = b2f(Yc[((size_t)b * Lc + l) * DM + ch]) * sc + sh;
            v = v > 0.f ? v : expm1f(v);  // ELU
            mx = fmaxf(mx, v);
        }
    }
    Out[((size_t)b * Lout + lp) * DM + ch] = __float2bfloat16(mx);
}

// ---------------- final projection to CO=7, dtype-matched store ----------------
__global__ __launch_bounds__(256) void fc_k(
    const bf16* __restrict__ Yn, const void* __restrict__ fcw, const void* __restrict__ fcb,
    void* __restrict__ out, int total, const int* __restrict__ flagp)
{
    const int f = *flagp;
    int i = blockIdx.x * 256 + threadIdx.x;
    if (i >= total) return;
    const int r = i / 7, co = i % 7;
    const bf16* yr = Yn + (size_t)r * DM;
    float acc = ldw(fcb, co, f);
    for (int d = 0; d < DM; ++d) acc += b2f(yr[d]) * ldw(fcw, d * 7 + co, f);
    if (f) ((bf16*)out)[i] = __float2bfloat16(acc);
    else   ((float*)out)[i] = acc;
}

// =============================================================================
extern "C" void kernel_launch(void* const* d_in, const int* in_sizes, int n_in,
                              void* d_out, int out_size, void* d_ws, size_t ws_size,
                              hipStream_t stream)
{
    const void* x_enc      = d_in[0];
    const void* x_mark_enc = d_in[1];
    const void* x_dec      = d_in[2];
    const void* x_mark_dec = d_in[3];
    const void* enc_vw = d_in[4];
    const void* enc_vb = d_in[5];
    const void* enc_mw = d_in[6];
    const void* enc_mb = d_in[7];
    const void* dec_vw = d_in[8];
    const void* dec_vb = d_in[9];
    const void* dec_mw = d_in[10];
    const void* dec_mb = d_in[11];
    const void* eW    = d_in[12];
    const void* ebi   = d_in[13];
    const void* effw1 = d_in[14];
    const void* effb1 = d_in[15];
    const void* effw2 = d_in[16];
    const void* effb2 = d_in[17];
    const void* eln1  = d_in[18];
    const void* eln2  = d_in[19];
    const void* cw    = d_in[20];
    const void* cb    = d_in[21];
    const void* cbn_g = d_in[22];
    const void* cbn_b = d_in[23];
    const void* enc_norm = d_in[24];
    const void* dsW   = d_in[25];
    const void* dsb   = d_in[26];
    const void* dcW   = d_in[27];
    const void* dcb   = d_in[28];
    const void* dffw1 = d_in[29];
    const void* dffb1 = d_in[30];
    const void* dffw2 = d_in[31];
    const void* dffb2 = d_in[32];
    const void* dln   = d_in[33];
    const void* dec_norm = d_in[34];
    const void* fcw   = d_in[35];
    const void* fcb   = d_in[36];

    // ---- workspace layout (~90 MiB; 111 MiB footprint ran clean in round 1) ----
    // X    [0, 8M)      : encoder acts; MEM + Yd in decoder phase
    // QKV  [8M, 40M)    : fused QKV / FFN hidden (aliased) / conv out / cross CQ+CKV
    // OUT  [40M, 48M)   : O-proj / FFN2 dest
    // WT   [48M, ~86.8M): ALL transposed weights (one-time prologue)
    // misc [88M, ~90M)  : IDX0/IDX1, PART, STATS, FLAG
    char* wsp = (char*)d_ws;
    bf16* X    = (bf16*)wsp;
    bf16* QKV  = (bf16*)(wsp + ((size_t)8 << 20));
    bf16* HID  = QKV;                                 // FFN hidden aliases dead QKV
    bf16* OUT  = (bf16*)(wsp + ((size_t)40 << 20));
    bf16* WT   = (bf16*)(wsp + ((size_t)48 << 20));
    int*   IDX0 = (int*)(wsp + ((size_t)88 << 20));   // 3*16*514 = 24672 ints
    int*   IDX1 = IDX0 + 24672;                       // 3*16*259 = 12432 ints
    float* PART = (float*)(wsp + ((size_t)89 << 20));
    float* STATS= (float*)(wsp + ((size_t)89 << 20) + (1 << 18));
    int*   FLAG = (int*)(wsp + ((size_t)89 << 20) + (1 << 18) + 4096);
    bf16* MEMb = X;                                               // [2080][512]
    bf16* Yd   = (bf16*)(wsp + (size_t)16 * 130 * 512 * 2);       // [4096][512]

    // transposed weight sub-arenas (element offsets)
    bf16* WTE  = WT;                    // enc QKVO: (i*4+q)*262144
    bf16* EW1T = WT + 3145728;          // + i*1048576
    bf16* EW2T = WT + 6291456;          // + i*1048576
    bf16* CWT  = WT + 9437184;          // + i*786432
    bf16* DSWt = WT + 11010048;         // + (i*4+q)*262144
    bf16* DCWt = WT + 13107200;
    bf16* DW1T = WT + 15204352;
    bf16* DW2T = WT + 17301504;

    auto cdiv = [](int a, int b) { return (a + b - 1) / b; };
    auto gemm = [&](const bf16* A, const bf16* Wt, const void* bias, unsigned boff,
                    bf16* C, int M, int N, int K, int lda, int ldc, bool relu) {
        dim3 g(N / 128, cdiv(M, 128));
        if (relu) mgemm_k<false, true><<<g, 256, 0, stream>>>(
            (const short*)A, nullptr, (const short*)Wt, bias, boff, C, M, N, K, lda, ldc, FLAG);
        else      mgemm_k<false, false><<<g, 256, 0, stream>>>(
            (const short*)A, nullptr, (const short*)Wt, bias, boff, C, M, N, K, lda, ldc, FLAG);
    };
    auto gemm64 = [&](const bf16* A, const bf16* Wt, const void* bias, unsigned boff,
                      bf16* C, int M, int N, int K, int lda, int ldc) {
        dim3 g(N / 64, cdiv(M, 128));
        mgemm64_k<false, false><<<g, 128, 0, stream>>>(
            (const short*)A, nullptr, (const short*)Wt, bias, boff, C, M, N, K, lda, ldc, FLAG);
    };
    auto transp = [&](const void* W, unsigned zstride, int nz, bf16* out, int K, int N) {
        transp_k<<<dim3(N / 32, K / 32, nz), 256, 0, stream>>>(W, 0u, zstride, out, K, N, FLAG);
    };

    // ---- prologue: sniff, all weight transposes, conv indices, embeddings ----
    sniff_k<<<1, 256, 0, stream>>>((const unsigned*)x_mark_enc, 16384, FLAG);
    transp(eW,    262144u, 12, WTE,  512, 512);
    transp(effw1, 1048576u, 3, EW1T, 512, 2048);
    transp(effw2, 1048576u, 3, EW2T, 2048, 512);
    convw_k<<<cdiv(1572864, 256), 256, 0, stream>>>(cw, CWT, 1572864, FLAG);
    transp(dsW,   262144u, 8, DSWt, 512, 512);
    transp(dcW,   262144u, 8, DCWt, 512, 512);
    transp(dffw1, 1048576u, 2, DW1T, 512, 2048);
    transp(dffw2, 1048576u, 2, DW2T, 2048, 512);
    convidx_k<<<cdiv(24672, 256), 256, 0, stream>>>(IDX0, 514, 512, 24672);
    convidx_k<<<cdiv(12432, 256), 256, 0, stream>>>(IDX1, 259, 257, 12432);
    embed_k<<<cdiv(16 * 512 * 512, 256), 256, 0, stream>>>(
        x_enc, enc_vw, enc_vb, x_mark_enc, enc_mw, enc_mb, X, 16 * 512, 7, 4, FLAG);

    // ---- encoder ----
    int L = 512;
    for (int i = 0; i < 3; ++i) {
        const int rows = 16 * L;
        const unsigned b0 = (unsigned)i * 4u * 512u;
        gemm(X, WTE + (size_t)i * 4 * 262144, ebi, b0, QKV, rows, 1536, 512, 512, 1536, false);
        fattn_k<0><<<dim3(cdiv(L, 16), 8, 16), 256, 0, stream>>>(
            QKV, QKV + 512, QKV + 1024, 1536, 1536, L, L);
        gemm64(QKV, WTE + (size_t)(i * 4 + 3) * 262144, ebi, b0 + 1536u, OUT, rows, 512, 512, 1536, 512);
        ln_off_k<<<rows, 256, 0, stream>>>(X, OUT, eln1, (unsigned)i * 1024u, X, FLAG);

        gemm(X, EW1T + (size_t)i * 1048576, effb1, (unsigned)i * 2048u, HID, rows, 2048, 512, 512, 2048, true);
        gemm64(HID, EW2T + (size_t)i * 1048576, effb2, (unsigned)i * 512u, OUT, rows, 512, 2048, 2048, 512);
        ln_off_k<<<rows, 256, 0, stream>>>(X, OUT, eln2, (unsigned)i * 1024u, X, FLAG);

        if (i < 2) {
            const int Lc = L + 2, Mc = 16 * Lc;
            const int* IDXi = (i == 0) ? IDX0 : IDX1;
            mgemm64_k<true, false><<<dim3(8, cdiv(Mc, 128)), 128, 0, stream>>>(
                (const short*)X, IDXi, (const short*)(CWT + (size_t)i * 786432),
                cb, (unsigned)i * 512u, QKV, Mc, 512, 1536, 512, 512, FLAG);
            bnstat1_k<<<32, 256, 0, stream>>>(QKV, PART, Mc);
            bnstat2_k<<<2, 256, 0, stream>>>(PART, STATS, 32, Mc);
            const int Lout = (L + 1) / 2 + 1;   // 514->257, 259->130
            const int tot = 16 * Lout * 512;
            bnpool_k<<<cdiv(tot, 256), 256, 0, stream>>>(
                QKV, STATS, cbn_g, cbn_b, (unsigned)i * 512u, X, Lc, Lout, tot, FLAG);
            L = Lout;
        }
    }
    const int Lm = L;  // 130
    ln_off_k<<<16 * Lm, 256, 0, stream>>>(X, nullptr, enc_norm, 0u, MEMb, FLAG);

    // ---- decoder embedding ----
    const int rowsD = 16 * 256;
    embed_k<<<cdiv(rowsD * 512, 256), 256, 0, stream>>>(
        x_dec, dec_vw, dec_vb, x_mark_dec, dec_mw, dec_mb, Yd, rowsD, 7, 4, FLAG);

    // ---- decoder ----
    bf16* CQ  = QKV;                       // [4096][512]
    bf16* CKV = QKV + (size_t)4096 * 512;  // [2080][1024]
    for (int i = 0; i < 2; ++i) {
        const unsigned b0 = (unsigned)i * 4u * 512u;
        // self-attention
        gemm(Yd, DSWt + (size_t)i * 4 * 262144, dsb, b0, QKV, rowsD, 1536, 512, 512, 1536, false);
        fattn_k<1><<<dim3(16, 8, 16), 256, 0, stream>>>(
            QKV, QKV + 512, QKV + 1024, 1536, 1536, 256, 256);
        gemm64(QKV, DSWt + (size_t)(i * 4 + 3) * 262144, dsb, b0 + 1536u, OUT, rowsD, 512, 512, 1536, 512);
        ln_off_k<<<rowsD, 256, 0, stream>>>(Yd, OUT, dln, (unsigned)(i * 3 + 0) * 1024u, Yd, FLAG);

        // cross-attention
        gemm64(Yd, DCWt + (size_t)i * 4 * 262144, dcb, b0, CQ, rowsD, 512, 512, 512, 512);
        gemm(MEMb, DCWt + (size_t)(i * 4 + 1) * 262144, dcb, b0 + 512u, CKV, 16 * Lm, 1024, 512, 512, 1024, false);
        fattn_k<2><<<dim3(16, 8, 16), 256, 0, stream>>>(
            CQ, CKV, CKV + 512, 512, 1024, 256, Lm);
        gemm64(CQ, DCWt + (size_t)(i * 4 + 3) * 262144, dcb, b0 + 1536u, OUT, rowsD, 512, 512, 512, 512);
        ln_off_k<<<rowsD, 256, 0, stream>>>(Yd, OUT, dln, (unsigned)(i * 3 + 1) * 1024u, Yd, FLAG);

        // FFN
        gemm(Yd, DW1T + (size_t)i * 1048576, dffb1, (unsigned)i * 2048u, HID, rowsD, 2048, 512, 512, 2048, true);
        gemm64(HID, DW2T + (size_t)i * 1048576, dffb2, (unsigned)i * 512u, OUT, rowsD, 512, 2048, 2048, 512);
        ln_off_k<<<rowsD, 256, 0, stream>>>(Yd, OUT, dln, (unsigned)(i * 3 + 2) * 1024u, Yd, FLAG);
    }

    ln_off_k<<<rowsD, 256, 0, stream>>>(Yd, nullptr, dec_norm, 0u, OUT, FLAG);
    fc_k<<<cdiv(rowsD * 7, 256), 256, 0, stream>>>(OUT, fcw, fcb, d_out, rowsD * 7, FLAG);
}